// Round 3
// baseline (2522.764 us; speedup 1.0000x reference)
//
#include <hip/hip_runtime.h>
#include <math.h>

#define H 128
#define NCLS 10
#define EPS 1e-5f
#define BN_BETA 1e-4f

typedef unsigned short u16;
typedef unsigned int u32;
typedef __attribute__((ext_vector_type(8))) short short8;
typedef __attribute__((ext_vector_type(4))) float floatx4;

// ---- bf16 helpers (bit ops; RNE) ----
__device__ inline float bflo(u32 u) { union { u32 i; float f; } a; a.i = u << 16; return a.f; }
__device__ inline float bfhi(u32 u) { union { u32 i; float f; } a; a.i = u & 0xffff0000u; return a.f; }
__device__ inline u16 f2bf(float f) {
  union { float f; u32 i; } v; v.f = f;
  return (u16)((v.i + 0x7fff + ((v.i >> 16) & 1)) >> 16);
}
__device__ inline u32 pack2(float a, float b) { return (u32)f2bf(a) | ((u32)f2bf(b) << 16); }

// ---------------- x fp32 -> bf16 ----------------
__global__ __launch_bounds__(256) void xcvt_kernel(const float* __restrict__ x,
                                                   u16* __restrict__ xb, int n4) {
  int i = blockIdx.x * 256 + threadIdx.x;
  if (i >= n4) return;
  float4 v = ((const float4*)x)[i];
  ((uint2*)xb)[i] = make_uint2(pack2(v.x, v.y), pack2(v.z, v.w));
}

// ---------------- column stats over bf16 [N,128], uint4 loads ----------------
__global__ __launch_bounds__(256) void colstats_kernel(
    const u16* __restrict__ X, int N, float* __restrict__ sum, float* __restrict__ sumsq) {
  int li = threadIdx.x & 15;   // 16B chunk within row (8 cols)
  int rg = threadIdx.x >> 4;   // row group 0..15
  const uint4* T = (const uint4*)X;
  float s[8] = {0, 0, 0, 0, 0, 0, 0, 0}, q[8] = {0, 0, 0, 0, 0, 0, 0, 0};
  for (int r = blockIdx.x * 16 + rg; r < N; r += gridDim.x * 16) {
    uint4 u = T[(size_t)r * 16 + li];
    float f[8] = {bflo(u.x), bfhi(u.x), bflo(u.y), bfhi(u.y),
                  bflo(u.z), bfhi(u.z), bflo(u.w), bfhi(u.w)};
#pragma unroll
    for (int j = 0; j < 8; j++) { s[j] += f[j]; q[j] += f[j] * f[j]; }
  }
#pragma unroll
  for (int j = 0; j < 8; j++) {
    s[j] += __shfl_xor(s[j], 16); s[j] += __shfl_xor(s[j], 32);
    q[j] += __shfl_xor(q[j], 16); q[j] += __shfl_xor(q[j], 32);
  }
  if ((threadIdx.x & 48) == 0) {
#pragma unroll
    for (int j = 0; j < 8; j++) {
      atomicAdd(&sum[li * 8 + j], s[j]);
      atomicAdd(&sumsq[li * 8 + j], q[j]);
    }
  }
}

// ---------------- fold BN into W: Wt_bf[k][f]=s_f*W[f][k] (bf16, transposed) ----
__global__ __launch_bounds__(128) void fold_kernel(
    const float* __restrict__ W, const float* __restrict__ bias,
    const float* __restrict__ sum, const float* __restrict__ sumsq, float invN,
    u16* __restrict__ Wt_bf, float* __restrict__ cout_) {
  int k = blockIdx.x;
  int f = threadIdx.x;
  float mu = sum[f] * invN;
  float var = sumsq[f] * invN - mu * mu;
  float s = 1.0f / sqrtf(fmaxf(var, 0.f) + EPS);
  float w = W[(size_t)f * H + k];
  Wt_bf[(size_t)k * H + f] = f2bf(s * w);
  __shared__ float red[H];
  red[f] = (BN_BETA - mu * s) * w;
  __syncthreads();
  for (int o = 64; o > 0; o >>= 1) {
    if (f < o) red[f] += red[f + o];
    __syncthreads();
  }
  if (f == 0) cout_[k] = red[0] + (bias ? bias[k] : 0.f);
}

// ---------------- fold for fc2 (Kout=10), fp32 out ----------------
__global__ __launch_bounds__(128) void fold10_kernel(
    const float* __restrict__ W, const float* __restrict__ bias,
    const float* __restrict__ sum, const float* __restrict__ sumsq, float invN,
    float* __restrict__ Wout, float* __restrict__ cout_) {
  int k = blockIdx.x;
  int f = threadIdx.x;
  float mu = sum[f] * invN;
  float var = sumsq[f] * invN - mu * mu;
  float s = 1.0f / sqrtf(fmaxf(var, 0.f) + EPS);
  float w = W[(size_t)f * NCLS + k];
  Wout[(size_t)f * NCLS + k] = s * w;
  __shared__ float red[H];
  red[f] = (BN_BETA - mu * s) * w;
  __syncthreads();
  for (int o = 64; o > 0; o >>= 1) {
    if (f < o) red[f] += red[f + o];
    __syncthreads();
  }
  if (f == 0) cout_[k] = red[0] + bias[k];
}

// ---------------- bf16 MFMA GEMM + optional fused colstats epilogue ----------------
__global__ __launch_bounds__(256) void gemm_kernel(
    const u16* __restrict__ A, const u16* __restrict__ Bt,
    const float* __restrict__ bias, u16* __restrict__ C, int N, int relu,
    float* __restrict__ st_sum, float* __restrict__ st_sumsq) {
  __shared__ float sred[4][H][2];
  int tid = threadIdx.x;
  int wave = tid >> 6, lane = tid & 63;
  int l15 = lane & 15, quad = lane >> 4;
  int row0 = (blockIdx.x * 4 + wave) * 16;
  int arow = row0 + l15;
  short8 a[4];
  short8 z8 = {0, 0, 0, 0, 0, 0, 0, 0};
#pragma unroll
  for (int k4 = 0; k4 < 4; k4++)
    a[k4] = (arow < N) ? *(const short8*)(A + (size_t)arow * H + k4 * 32 + quad * 8) : z8;
  float ps[8], pq[8];
#pragma unroll
  for (int nt = 0; nt < 8; nt++) {
    floatx4 acc = {0.f, 0.f, 0.f, 0.f};
    const u16* bp = Bt + (size_t)(nt * 16 + l15) * H + quad * 8;
#pragma unroll
    for (int k4 = 0; k4 < 4; k4++) {
      short8 b = *(const short8*)(bp + k4 * 32);
      acc = __builtin_amdgcn_mfma_f32_16x16x32_bf16(a[k4], b, acc, 0, 0, 0);
    }
    int col = nt * 16 + l15;
    float bs = bias[col];
    float s_ = 0.f, q_ = 0.f;
#pragma unroll
    for (int r = 0; r < 4; r++) {
      int row = row0 + quad * 4 + r;
      if (row < N) {
        float v = acc[r] + bs;
        if (relu) v = fmaxf(v, 0.f);
        s_ += v; q_ += v * v;
        C[(size_t)row * H + col] = f2bf(v);
      }
    }
    ps[nt] = s_; pq[nt] = q_;
  }
  if (st_sum) {
#pragma unroll
    for (int nt = 0; nt < 8; nt++) {
      ps[nt] += __shfl_xor(ps[nt], 16); ps[nt] += __shfl_xor(ps[nt], 32);
      pq[nt] += __shfl_xor(pq[nt], 16); pq[nt] += __shfl_xor(pq[nt], 32);
    }
    if (quad == 0) {
#pragma unroll
      for (int nt = 0; nt < 8; nt++) {
        sred[wave][nt * 16 + l15][0] = ps[nt];
        sred[wave][nt * 16 + l15][1] = pq[nt];
      }
    }
    __syncthreads();
    int col = tid & 127, stat = tid >> 7;
    float sv = sred[0][col][stat] + sred[1][col][stat] + sred[2][col][stat] + sred[3][col][stat];
    atomicAdd(stat ? &st_sumsq[col] : &st_sum[col], sv);
  }
}

// ---------------- CSR build ----------------
__global__ __launch_bounds__(256) void hist_kernel(
    const int* __restrict__ row, const int* __restrict__ col, int E,
    int* __restrict__ cnt, float* __restrict__ deg) {
  int e = blockIdx.x * 256 + threadIdx.x;
  if (e < E) {
    atomicAdd(&cnt[col[e]], 1);
    atomicAdd(&deg[row[e]], 1.0f);
  }
}

__global__ __launch_bounds__(256) void scanA_kernel(const int* __restrict__ cnt, int N,
                                                    int* __restrict__ partial) {
  __shared__ int sd[256];
  int i = blockIdx.x * 256 + threadIdx.x;
  sd[threadIdx.x] = (i < N) ? cnt[i] : 0;
  __syncthreads();
  for (int o = 128; o > 0; o >>= 1) {
    if (threadIdx.x < o) sd[threadIdx.x] += sd[threadIdx.x + o];
    __syncthreads();
  }
  if (threadIdx.x == 0) partial[blockIdx.x] = sd[0];
}

__global__ __launch_bounds__(256) void scanB_kernel(const int* __restrict__ partial, int nb,
                                                    int* __restrict__ blockoff) {
  __shared__ int sd[256];
  int t = threadIdx.x;
  int v = (t < nb) ? partial[t] : 0;
  sd[t] = v;
  __syncthreads();
  for (int o = 1; o < 256; o <<= 1) {
    int x = (t >= o) ? sd[t - o] : 0;
    __syncthreads();
    sd[t] += x;
    __syncthreads();
  }
  blockoff[t] = sd[t] - v;
}

__global__ __launch_bounds__(256) void scanC_kernel(
    const int* __restrict__ cnt, int N, const int* __restrict__ blockoff,
    int* __restrict__ off, int* __restrict__ cur, int E) {
  __shared__ int sd[256];
  int t = threadIdx.x;
  int i = blockIdx.x * 256 + t;
  int v = (i < N) ? cnt[i] : 0;
  sd[t] = v;
  __syncthreads();
  for (int o = 1; o < 256; o <<= 1) {
    int x = (t >= o) ? sd[t - o] : 0;
    __syncthreads();
    sd[t] += x;
    __syncthreads();
  }
  if (i < N) {
    int ex = blockoff[blockIdx.x] + sd[t] - v;
    off[i] = ex;
    cur[i] = ex;
  }
  if (i == 0) off[N] = E;
}

__global__ __launch_bounds__(256) void place_kernel(
    const int* __restrict__ row, const int* __restrict__ col, int E,
    int* __restrict__ cur, int* __restrict__ csr_src, int* __restrict__ csr_eid) {
  int e = blockIdx.x * 256 + threadIdx.x;
  if (e < E) {
    int slot = atomicAdd(&cur[col[e]], 1);
    csr_src[slot] = row[e];
    csr_eid[slot] = e;
  }
}

__global__ __launch_bounds__(256) void rsqrt_kernel(const float* __restrict__ deg,
                                                    float* __restrict__ dinv, int N) {
  int v = blockIdx.x * 256 + threadIdx.x;
  if (v < N) dinv[v] = 1.0f / sqrtf(deg[v] + 1.0f);
}

__global__ __launch_bounds__(256) void rsqrt2_kernel(
    const float* __restrict__ a, const float* __restrict__ b,
    float* __restrict__ oa, float* __restrict__ ob, int N) {
  int v = blockIdx.x * 256 + threadIdx.x;
  if (v < N) {
    oa[v] = 1.0f / sqrtf(a[v] + 1.0f);
    ob[v] = 1.0f / sqrtf(b[v] + 1.0f);
  }
}

// ---------------- aggregation: 4 groups x 16 lanes, 4 edges in flight ----------------
#define AGG_BODY(WEXPR)                                                        \
  for (int s = s0; s < s1; s += 4) {                                           \
    int e = s + g;                                                             \
    int src = v; float w = 0.f;                                                \
    if (e < s1) { src = csr_src[e]; WEXPR; }                                   \
    uint4 u = T[(size_t)src * 16 + li];                                        \
    acc[0] += w * bflo(u.x); acc[1] += w * bfhi(u.x);                          \
    acc[2] += w * bflo(u.y); acc[3] += w * bfhi(u.y);                          \
    acc[4] += w * bflo(u.z); acc[5] += w * bfhi(u.z);                          \
    acc[6] += w * bflo(u.w); acc[7] += w * bfhi(u.w);                          \
  }

__global__ __launch_bounds__(256) void agg_kernel(
    const u16* __restrict__ t, const int* __restrict__ csr_src,
    const int* __restrict__ csr_eid, const float* __restrict__ att,
    const int* __restrict__ off, const float* __restrict__ dinv,
    const float* __restrict__ bias, u16* __restrict__ out, int N) {
  int v = blockIdx.x * 4 + (threadIdx.x >> 6);
  if (v >= N) return;
  int lane = threadIdx.x & 63;
  int g = lane >> 4, li = lane & 15;
  const uint4* T = (const uint4*)t;
  float dv = dinv[v];
  float acc[8] = {0.f, 0.f, 0.f, 0.f, 0.f, 0.f, 0.f, 0.f};
  if (g == 0) {
    uint4 u = T[(size_t)v * 16 + li];
    float w0 = dv * dv;
    acc[0] = w0 * bflo(u.x); acc[1] = w0 * bfhi(u.x);
    acc[2] = w0 * bflo(u.y); acc[3] = w0 * bfhi(u.y);
    acc[4] = w0 * bflo(u.z); acc[5] = w0 * bfhi(u.z);
    acc[6] = w0 * bflo(u.w); acc[7] = w0 * bfhi(u.w);
  }
  int s0 = off[v], s1 = off[v + 1];
  if (att) {
#pragma unroll 2
    AGG_BODY(w = dinv[src] * dv * att[csr_eid[e]])
  } else {
#pragma unroll 2
    AGG_BODY(w = dinv[src] * dv)
  }
#pragma unroll
  for (int j = 0; j < 8; j++) {
    acc[j] += __shfl_xor(acc[j], 16);
    acc[j] += __shfl_xor(acc[j], 32);
  }
  if (g == 0) {
    float o[8];
#pragma unroll
    for (int j = 0; j < 8; j++) o[j] = fmaxf(acc[j] + bias[li * 8 + j], 0.f);
    uint4 w4;
    w4.x = pack2(o[0], o[1]); w4.y = pack2(o[2], o[3]);
    w4.z = pack2(o[4], o[5]); w4.w = pack2(o[6], o[7]);
    ((uint4*)out)[(size_t)v * 16 + li] = w4;
  }
}

// ---------------- node attention + edge-att p,q factors ----------------
__global__ __launch_bounds__(256) void natt_kernel(
    const u16* __restrict__ h, int N,
    const float* __restrict__ W_na, const float* __restrict__ b_na,
    const float* __restrict__ W_ea,
    float* __restrict__ na0, float* __restrict__ na1,
    float* __restrict__ p0, float* __restrict__ p1,
    float* __restrict__ q0, float* __restrict__ q1) {
  int n = blockIdx.x * 256 + threadIdx.x;
  if (n >= N) return;
  float sa0 = 0, sa1 = 0, sp0 = 0, sp1 = 0, sq0 = 0, sq1 = 0;
  const uint2* hr = (const uint2*)(h + (size_t)n * H);
  for (int c = 0; c < 32; c++) {
    uint2 u = hr[c];
    float v0 = bflo(u.x), v1 = bfhi(u.x), v2 = bflo(u.y), v3 = bfhi(u.y);
    int k = c * 4;
    sa0 += v0 * W_na[k * 2] + v1 * W_na[k * 2 + 2] + v2 * W_na[k * 2 + 4] + v3 * W_na[k * 2 + 6];
    sa1 += v0 * W_na[k * 2 + 1] + v1 * W_na[k * 2 + 3] + v2 * W_na[k * 2 + 5] + v3 * W_na[k * 2 + 7];
    sp0 += v0 * W_ea[k * 2] + v1 * W_ea[k * 2 + 2] + v2 * W_ea[k * 2 + 4] + v3 * W_ea[k * 2 + 6];
    sp1 += v0 * W_ea[k * 2 + 1] + v1 * W_ea[k * 2 + 3] + v2 * W_ea[k * 2 + 5] + v3 * W_ea[k * 2 + 7];
    sq0 += v0 * W_ea[(H + k) * 2] + v1 * W_ea[(H + k) * 2 + 2] + v2 * W_ea[(H + k) * 2 + 4] + v3 * W_ea[(H + k) * 2 + 6];
    sq1 += v0 * W_ea[(H + k) * 2 + 1] + v1 * W_ea[(H + k) * 2 + 3] + v2 * W_ea[(H + k) * 2 + 5] + v3 * W_ea[(H + k) * 2 + 7];
  }
  sa0 += b_na[0]; sa1 += b_na[1];
  float m = fmaxf(sa0, sa1);
  float e0 = expf(sa0 - m), e1 = expf(sa1 - m);
  float inv = 1.f / (e0 + e1);
  na0[n] = e0 * inv; na1[n] = e1 * inv;
  p0[n] = sp0; p1[n] = sp1; q0[n] = sq0; q1[n] = sq1;
}

// ---------------- xc_pre = na0*h, xo_pre = na1*h ----------------
__global__ __launch_bounds__(256) void xpre_kernel(
    const u16* __restrict__ h, const float* __restrict__ na0,
    const float* __restrict__ na1, u16* __restrict__ xc, u16* __restrict__ xo, int n4) {
  int i = blockIdx.x * 256 + threadIdx.x;
  if (i >= n4) return;
  int n = i >> 5;
  uint2 u = ((const uint2*)h)[i];
  float v0 = bflo(u.x), v1 = bfhi(u.x), v2 = bflo(u.y), v3 = bfhi(u.y);
  float a = na0[n], b = na1[n];
  ((uint2*)xc)[i] = make_uint2(pack2(v0 * a, v1 * a), pack2(v2 * a, v3 * a));
  ((uint2*)xo)[i] = make_uint2(pack2(v0 * b, v1 * b), pack2(v2 * b, v3 * b));
}

// ---------------- edge attention + weighted degree ----------------
__global__ __launch_bounds__(256) void eatt_kernel(
    const int* __restrict__ row, const int* __restrict__ col, int E,
    const float* __restrict__ p0, const float* __restrict__ p1,
    const float* __restrict__ q0, const float* __restrict__ q1,
    const float* __restrict__ b_ea,
    float* __restrict__ att0, float* __restrict__ att1,
    float* __restrict__ degc, float* __restrict__ dego) {
  int e = blockIdx.x * 256 + threadIdx.x;
  if (e >= E) return;
  int r = row[e], c = col[e];
  float l0 = p0[r] + q0[c] + b_ea[0];
  float l1 = p1[r] + q1[c] + b_ea[1];
  float m = fmaxf(l0, l1);
  float e0 = expf(l0 - m), e1 = expf(l1 - m);
  float inv = 1.f / (e0 + e1);
  float a0 = e0 * inv, a1 = e1 * inv;
  att0[e] = a0; att1[e] = a1;
  atomicAdd(&degc[r], a0);
  atomicAdd(&dego[r], a1);
}

// ---------------- h_co = xc[perm] + xo ----------------
__global__ __launch_bounds__(256) void permadd_kernel(
    const u16* __restrict__ xc, const u16* __restrict__ xo,
    const int* __restrict__ perm, u16* __restrict__ out, int n4) {
  int i = blockIdx.x * 256 + threadIdx.x;
  if (i >= n4) return;
  int n = i >> 5, k = i & 31;
  int p = perm[n];
  uint2 a = ((const uint2*)xc)[(size_t)p * 32 + k];
  uint2 b = ((const uint2*)xo)[i];
  ((uint2*)out)[i] = make_uint2(pack2(bflo(a.x) + bflo(b.x), bfhi(a.x) + bfhi(b.x)),
                                pack2(bflo(a.y) + bflo(b.y), bfhi(a.y) + bfhi(b.y)));
}

// ---------------- fc2 [N,128]@[128,10] + log_softmax ----------------
__global__ __launch_bounds__(256) void fc2_kernel(
    const u16* __restrict__ z, const float* __restrict__ W2,
    const float* __restrict__ c2, float* __restrict__ outp, int N) {
  int n = blockIdx.x * 256 + threadIdx.x;
  if (n >= N) return;
  float acc[NCLS];
#pragma unroll
  for (int c = 0; c < NCLS; c++) acc[c] = c2[c];
  const uint2* zr = (const uint2*)(z + (size_t)n * H);
  for (int c4 = 0; c4 < 32; c4++) {
    uint2 u = zr[c4];
    float v[4] = {bflo(u.x), bfhi(u.x), bflo(u.y), bfhi(u.y)};
    int k = c4 * 4;
#pragma unroll
    for (int j = 0; j < 4; j++)
#pragma unroll
      for (int c = 0; c < NCLS; c++) acc[c] += v[j] * W2[(k + j) * NCLS + c];
  }
  float m = acc[0];
#pragma unroll
  for (int c = 1; c < NCLS; c++) m = fmaxf(m, acc[c]);
  float s = 0.f;
#pragma unroll
  for (int c = 0; c < NCLS; c++) s += expf(acc[c] - m);
  float lse = logf(s) + m;
#pragma unroll
  for (int c = 0; c < NCLS; c++) outp[(size_t)n * NCLS + c] = acc[c] - lse;
}

// =============================================================================
extern "C" void kernel_launch(void* const* d_in, const int* in_sizes, int n_in,
                              void* d_out, int out_size, void* d_ws, size_t ws_size,
                              hipStream_t stream) {
  const int N = in_sizes[0] / H;
  const int E = in_sizes[1] / 2;
  const float* x = (const float*)d_in[0];
  const int* ei = (const int*)d_in[1];
  const int* row = ei;
  const int* col = ei + E;
  const int* perm = (const int*)d_in[2];
  const float* W_feat = (const float*)d_in[3];
  const float* b_feat = (const float*)d_in[4];
  const float* W_convs = (const float*)d_in[5];
  const float* b_convs = (const float*)d_in[6];
  const float* W_ea = (const float*)d_in[7];
  const float* b_ea = (const float*)d_in[8];
  const float* W_na = (const float*)d_in[9];
  const float* b_na = (const float*)d_in[10];
  const float* W_ctx = (const float*)d_in[11];
  const float* b_ctx = (const float*)d_in[12];
  const float* W_obj = (const float*)d_in[13];
  const float* b_obj = (const float*)d_in[14];
  const float* W_fc1 = (const float*)d_in[15];
  const float* b_fc1 = (const float*)d_in[16];
  const float* W_fc2 = (const float*)d_in[17];
  const float* b_fc2 = (const float*)d_in[18];
  float* out = (float*)d_out;

  // ---------- workspace carve ----------
  char* base = (char*)d_ws;
  size_t off_b = 0;
  auto alloc = [&](size_t bytes) -> void* {
    void* p = base + off_b;
    off_b = (off_b + bytes + 255) & ~(size_t)255;
    return p;
  };
  size_t NB2 = (size_t)N * H * sizeof(u16);
  u16* bufA = (u16*)alloc(NB2);
  u16* bufB = (u16*)alloc(NB2);
  u16* bufC = (u16*)alloc(NB2);
  u16* bufD = (u16*)alloc(NB2);
  u16* xbf = (u16*)alloc(NB2);
  // zero-region: cnt, deg, degc, dego, 12 stat pairs (one memset)
  int* cnt = (int*)alloc((4 * (size_t)N + 12 * 256) * 4);
  float* deg = (float*)(cnt + N);
  float* degc = (float*)(cnt + 2 * (size_t)N);
  float* dego = (float*)(cnt + 3 * (size_t)N);
  float* stats = (float*)(cnt + 4 * (size_t)N);  // stats + i*256 (sum), +128 (sumsq)
  int* off = (int*)alloc(((size_t)N + 1) * 4);
  int* cur = (int*)alloc((size_t)N * 4);
  float* dinv = (float*)alloc((size_t)N * 4);
  float* dinvc = (float*)alloc((size_t)N * 4);
  float* dinvo = (float*)alloc((size_t)N * 4);
  float* na0 = (float*)alloc((size_t)N * 4);
  float* na1 = (float*)alloc((size_t)N * 4);
  float* p0 = (float*)alloc((size_t)N * 4);
  float* p1 = (float*)alloc((size_t)N * 4);
  float* q0 = (float*)alloc((size_t)N * 4);
  float* q1 = (float*)alloc((size_t)N * 4);
  int* partial = (int*)alloc(256 * 4);
  int* blockoff = (int*)alloc(256 * 4);
  u16* Wt = (u16*)alloc((size_t)H * H * 2);
  float* cf = (float*)alloc(H * 4);
  float* W2f = (float*)alloc((size_t)H * NCLS * 4);
  float* c2f = (float*)alloc(16 * 4);
  float* att0 = (float*)alloc((size_t)E * 4);
  float* att1 = (float*)alloc((size_t)E * 4);
  int* csr_src = (int*)alloc((size_t)E * 4);
  int* csr_eid = (int*)alloc((size_t)E * 4);

  const float invN = 1.0f / (float)N;
  const int gN = (N + 255) / 256;
  const int gE = (E + 255) / 256;
  const int SB = (N + 255) / 256;
  const int gG = (N + 63) / 64;
  const int n4 = N * 32;
  const int gV = (n4 + 255) / 256;
  const int gAgg = (N + 3) / 4;
  const int gCS = 256;  // colstats grid

#define ST(i) (stats + (i) * 256), (stats + (i) * 256 + 128)

  // ---------- one memset for all accumulators ----------
  hipMemsetAsync(cnt, 0, (4 * (size_t)N + 12 * 256) * 4, stream);

  // ---------- CSR + degrees ----------
  hist_kernel<<<gE, 256, 0, stream>>>(row, col, E, cnt, deg);
  scanA_kernel<<<SB, 256, 0, stream>>>(cnt, N, partial);
  scanB_kernel<<<1, 256, 0, stream>>>(partial, SB, blockoff);
  scanC_kernel<<<SB, 256, 0, stream>>>(cnt, N, blockoff, off, cur, E);
  place_kernel<<<gE, 256, 0, stream>>>(row, col, E, cur, csr_src, csr_eid);
  rsqrt_kernel<<<gN, 256, 0, stream>>>(deg, dinv, N);

  // ---------- feature layer: stats(x)->fold->gemm(+stats of h0) ----------
  xcvt_kernel<<<gV, 256, 0, stream>>>(x, xbf, n4);
  colstats_kernel<<<gCS, 256, 0, stream>>>(xbf, N, ST(0));
  fold_kernel<<<H, H, 0, stream>>>(W_feat, b_feat, ST(0), invN, Wt, cf);
  gemm_kernel<<<gG, 256, 0, stream>>>(xbf, Wt, cf, bufA, N, 1, ST(1));

  // ---------- 3 GCN convs (stats of h_i: st1 fused, st2/st3 via colstats) ----
  for (int i = 0; i < 3; ++i) {
    fold_kernel<<<H, H, 0, stream>>>(W_convs + (size_t)i * H * H, nullptr, ST(1 + i),
                                     invN, Wt, cf);
    gemm_kernel<<<gG, 256, 0, stream>>>(bufA, Wt, cf, bufC, N, 0, nullptr, nullptr);
    agg_kernel<<<gAgg, 256, 0, stream>>>(bufC, csr_src, csr_eid, nullptr, off, dinv,
                                         b_convs + (size_t)i * H, bufA, N);
    if (i < 2) colstats_kernel<<<gCS, 256, 0, stream>>>(bufA, N, ST(2 + i));
  }

  // ---------- attention ----------
  natt_kernel<<<gN, 256, 0, stream>>>(bufA, N, W_na, b_na, W_ea, na0, na1, p0, p1, q0, q1);
  eatt_kernel<<<gE, 256, 0, stream>>>(row, col, E, p0, p1, q0, q1, b_ea, att0, att1,
                                      degc, dego);
  rsqrt2_kernel<<<gN, 256, 0, stream>>>(degc, dego, dinvc, dinvo, N);
  xpre_kernel<<<gV, 256, 0, stream>>>(bufA, na0, na1, bufB, bufC, n4);
  colstats_kernel<<<gCS, 256, 0, stream>>>(bufB, N, ST(4));
  colstats_kernel<<<gCS, 256, 0, stream>>>(bufC, N, ST(5));

  // ---------- ctx conv ----------
  fold_kernel<<<H, H, 0, stream>>>(W_ctx, nullptr, ST(4), invN, Wt, cf);
  gemm_kernel<<<gG, 256, 0, stream>>>(bufB, Wt, cf, bufD, N, 0, nullptr, nullptr);
  agg_kernel<<<gAgg, 256, 0, stream>>>(bufD, csr_src, csr_eid, att0, off, dinvc, b_ctx,
                                       bufB, N);  // xc in B
  colstats_kernel<<<gCS, 256, 0, stream>>>(bufB, N, ST(6));

  // ---------- obj conv ----------
  fold_kernel<<<H, H, 0, stream>>>(W_obj, nullptr, ST(5), invN, Wt, cf);
  gemm_kernel<<<gG, 256, 0, stream>>>(bufC, Wt, cf, bufD, N, 0, nullptr, nullptr);
  agg_kernel<<<gAgg, 256, 0, stream>>>(bufD, csr_src, csr_eid, att1, off, dinvo, b_obj,
                                       bufA, N);  // xo in A
  colstats_kernel<<<gCS, 256, 0, stream>>>(bufA, N, ST(7));

  // ---------- h_co = xc[perm] + xo ----------
  permadd_kernel<<<gV, 256, 0, stream>>>(bufB, bufA, perm, bufD, n4);
  colstats_kernel<<<gCS, 256, 0, stream>>>(bufD, N, ST(8));

  // ---------- 3 readouts (z stats fused into fc1 gemm) ----------
  const u16* Xin[3] = {bufB, bufA, bufD};
  for (int j = 0; j < 3; ++j) {
    fold_kernel<<<H, H, 0, stream>>>(W_fc1 + (size_t)j * H * H, b_fc1 + (size_t)j * H,
                                     ST(6 + j), invN, Wt, cf);
    gemm_kernel<<<gG, 256, 0, stream>>>(Xin[j], Wt, cf, bufC, N, 1, ST(9 + j));
    fold10_kernel<<<NCLS, H, 0, stream>>>(W_fc2 + (size_t)j * H * NCLS,
                                          b_fc2 + (size_t)j * NCLS, ST(9 + j),
                                          invN, W2f, c2f);
    fc2_kernel<<<gN, 256, 0, stream>>>(bufC, W2f, c2f, out + (size_t)j * N * NCLS, N);
  }
#undef ST
}

// Round 4
// 1641.454 us; speedup vs baseline: 1.5369x; 1.5369x over previous
//
#include <hip/hip_runtime.h>
#include <math.h>

#define H 128
#define NCLS 10
#define EPS 1e-5f
#define BN_BETA 1e-4f
#define CS_BLOCKS 256  // colstats stage-1 blocks (= partial rows)

typedef unsigned short u16;
typedef unsigned int u32;
typedef __attribute__((ext_vector_type(8))) short short8;
typedef __attribute__((ext_vector_type(4))) float floatx4;

// ---- bf16 helpers (bit ops; RNE) ----
__device__ inline float bflo(u32 u) { union { u32 i; float f; } a; a.i = u << 16; return a.f; }
__device__ inline float bfhi(u32 u) { union { u32 i; float f; } a; a.i = u & 0xffff0000u; return a.f; }
__device__ inline u16 f2bf(float f) {
  union { float f; u32 i; } v; v.f = f;
  return (u16)((v.i + 0x7fff + ((v.i >> 16) & 1)) >> 16);
}
__device__ inline u32 pack2(float a, float b) { return (u32)f2bf(a) | ((u32)f2bf(b) << 16); }

// ---------------- x fp32 -> bf16 ----------------
__global__ __launch_bounds__(256) void xcvt_kernel(const float* __restrict__ x,
                                                   u16* __restrict__ xb, int n4) {
  int i = blockIdx.x * 256 + threadIdx.x;
  if (i >= n4) return;
  float4 v = ((const float4*)x)[i];
  ((uint2*)xb)[i] = make_uint2(pack2(v.x, v.y), pack2(v.z, v.w));
}

// ---------------- column stats stage 1: NO atomics, per-block partial row ----
// partial[b*256 + c] = block-b partial sum of col c (c<128) / sumsq of col c-128
__global__ __launch_bounds__(256) void colstats_kernel(
    const u16* __restrict__ X, int N, float* __restrict__ partial) {
  int tid = threadIdx.x;
  int li = tid & 15;   // 16B chunk within row (8 cols)
  int rg = tid >> 4;   // row group 0..15
  int wave = tid >> 6, lane = tid & 63;
  const uint4* T = (const uint4*)X;
  float s[8] = {0, 0, 0, 0, 0, 0, 0, 0}, q[8] = {0, 0, 0, 0, 0, 0, 0, 0};
  for (int r = blockIdx.x * 16 + rg; r < N; r += gridDim.x * 16) {
    uint4 u = T[(size_t)r * 16 + li];
    float f[8] = {bflo(u.x), bfhi(u.x), bflo(u.y), bfhi(u.y),
                  bflo(u.z), bfhi(u.z), bflo(u.w), bfhi(u.w)};
#pragma unroll
    for (int j = 0; j < 8; j++) { s[j] += f[j]; q[j] += f[j] * f[j]; }
  }
#pragma unroll
  for (int j = 0; j < 8; j++) {
    s[j] += __shfl_xor(s[j], 16); s[j] += __shfl_xor(s[j], 32);
    q[j] += __shfl_xor(q[j], 16); q[j] += __shfl_xor(q[j], 32);
  }
  __shared__ float sm[4][256];
  if ((lane & 48) == 0) {
#pragma unroll
    for (int j = 0; j < 8; j++) {
      sm[wave][li * 8 + j] = s[j];
      sm[wave][128 + li * 8 + j] = q[j];
    }
  }
  __syncthreads();
  float v = sm[0][tid] + sm[1][tid] + sm[2][tid] + sm[3][tid];
  partial[(size_t)blockIdx.x * 256 + tid] = v;
}

// ---------------- fold: reduce partials + BN-fold into W (bf16, transposed) ----
__global__ __launch_bounds__(128) void fold_kernel(
    const float* __restrict__ partial, int nb,
    const float* __restrict__ W, const float* __restrict__ bias, float invN,
    u16* __restrict__ Wt_bf, float* __restrict__ cout_) {
  int k = blockIdx.x;
  int f = threadIdx.x;
  float su = 0.f, sq = 0.f;
  for (int b = 0; b < nb; b++) {
    su += partial[(size_t)b * 256 + f];
    sq += partial[(size_t)b * 256 + 128 + f];
  }
  float mu = su * invN;
  float var = sq * invN - mu * mu;
  float s = 1.0f / sqrtf(fmaxf(var, 0.f) + EPS);
  float w = W[(size_t)f * H + k];
  Wt_bf[(size_t)k * H + f] = f2bf(s * w);
  __shared__ float red[H];
  red[f] = (BN_BETA - mu * s) * w;
  __syncthreads();
  for (int o = 64; o > 0; o >>= 1) {
    if (f < o) red[f] += red[f + o];
    __syncthreads();
  }
  if (f == 0) cout_[k] = red[0] + (bias ? bias[k] : 0.f);
}

// ---------------- fold for fc2 (Kout=10), fp32 out ----------------
__global__ __launch_bounds__(128) void fold10_kernel(
    const float* __restrict__ partial, int nb,
    const float* __restrict__ W, const float* __restrict__ bias, float invN,
    float* __restrict__ Wout, float* __restrict__ cout_) {
  int k = blockIdx.x;
  int f = threadIdx.x;
  float su = 0.f, sq = 0.f;
  for (int b = 0; b < nb; b++) {
    su += partial[(size_t)b * 256 + f];
    sq += partial[(size_t)b * 256 + 128 + f];
  }
  float mu = su * invN;
  float var = sq * invN - mu * mu;
  float s = 1.0f / sqrtf(fmaxf(var, 0.f) + EPS);
  float w = W[(size_t)f * NCLS + k];
  Wout[(size_t)f * NCLS + k] = s * w;
  __shared__ float red[H];
  red[f] = (BN_BETA - mu * s) * w;
  __syncthreads();
  for (int o = 64; o > 0; o >>= 1) {
    if (f < o) red[f] += red[f + o];
    __syncthreads();
  }
  if (f == 0) cout_[k] = red[0] + bias[k];
}

// ---------------- bf16 MFMA GEMM: C[N,128] = A[N,128] @ Wt^T + c ----------------
__global__ __launch_bounds__(256) void gemm_kernel(
    const u16* __restrict__ A, const u16* __restrict__ Bt,
    const float* __restrict__ bias, u16* __restrict__ C, int N, int relu) {
  int tid = threadIdx.x;
  int wave = tid >> 6, lane = tid & 63;
  int l15 = lane & 15, quad = lane >> 4;
  int row0 = (blockIdx.x * 4 + wave) * 16;
  if (row0 >= N) return;
  int arow = row0 + l15;
  short8 a[4];
  short8 z8 = {0, 0, 0, 0, 0, 0, 0, 0};
#pragma unroll
  for (int k4 = 0; k4 < 4; k4++)
    a[k4] = (arow < N) ? *(const short8*)(A + (size_t)arow * H + k4 * 32 + quad * 8) : z8;
#pragma unroll
  for (int nt = 0; nt < 8; nt++) {
    floatx4 acc = {0.f, 0.f, 0.f, 0.f};
    const u16* bp = Bt + (size_t)(nt * 16 + l15) * H + quad * 8;
#pragma unroll
    for (int k4 = 0; k4 < 4; k4++) {
      short8 b = *(const short8*)(bp + k4 * 32);
      acc = __builtin_amdgcn_mfma_f32_16x16x32_bf16(a[k4], b, acc, 0, 0, 0);
    }
    int col = nt * 16 + l15;
    float bs = bias[col];
#pragma unroll
    for (int r = 0; r < 4; r++) {
      int row = row0 + quad * 4 + r;
      if (row < N) {
        float v = acc[r] + bs;
        if (relu) v = fmaxf(v, 0.f);
        C[(size_t)row * H + col] = f2bf(v);
      }
    }
  }
}

// ---------------- CSR build ----------------
__global__ __launch_bounds__(256) void hist_kernel(
    const int* __restrict__ row, const int* __restrict__ col, int E,
    int* __restrict__ cnt, float* __restrict__ deg) {
  int e = blockIdx.x * 256 + threadIdx.x;
  if (e < E) {
    atomicAdd(&cnt[col[e]], 1);
    atomicAdd(&deg[row[e]], 1.0f);
  }
}

__global__ __launch_bounds__(256) void scanA_kernel(const int* __restrict__ cnt, int N,
                                                    int* __restrict__ partial) {
  __shared__ int sd[256];
  int i = blockIdx.x * 256 + threadIdx.x;
  sd[threadIdx.x] = (i < N) ? cnt[i] : 0;
  __syncthreads();
  for (int o = 128; o > 0; o >>= 1) {
    if (threadIdx.x < o) sd[threadIdx.x] += sd[threadIdx.x + o];
    __syncthreads();
  }
  if (threadIdx.x == 0) partial[blockIdx.x] = sd[0];
}

__global__ __launch_bounds__(256) void scanB_kernel(const int* __restrict__ partial, int nb,
                                                    int* __restrict__ blockoff) {
  __shared__ int sd[256];
  int t = threadIdx.x;
  int v = (t < nb) ? partial[t] : 0;
  sd[t] = v;
  __syncthreads();
  for (int o = 1; o < 256; o <<= 1) {
    int x = (t >= o) ? sd[t - o] : 0;
    __syncthreads();
    sd[t] += x;
    __syncthreads();
  }
  blockoff[t] = sd[t] - v;
}

__global__ __launch_bounds__(256) void scanC_kernel(
    const int* __restrict__ cnt, int N, const int* __restrict__ blockoff,
    int* __restrict__ off, int* __restrict__ cur, int E) {
  __shared__ int sd[256];
  int t = threadIdx.x;
  int i = blockIdx.x * 256 + t;
  int v = (i < N) ? cnt[i] : 0;
  sd[t] = v;
  __syncthreads();
  for (int o = 1; o < 256; o <<= 1) {
    int x = (t >= o) ? sd[t - o] : 0;
    __syncthreads();
    sd[t] += x;
    __syncthreads();
  }
  if (i < N) {
    int ex = blockoff[blockIdx.x] + sd[t] - v;
    off[i] = ex;
    cur[i] = ex;
  }
  if (i == 0) off[N] = E;
}

__global__ __launch_bounds__(256) void place_kernel(
    const int* __restrict__ row, const int* __restrict__ col, int E,
    int* __restrict__ cur, int* __restrict__ csr_src, int* __restrict__ csr_eid) {
  int e = blockIdx.x * 256 + threadIdx.x;
  if (e < E) {
    int slot = atomicAdd(&cur[col[e]], 1);
    csr_src[slot] = row[e];
    csr_eid[slot] = e;
  }
}

__global__ __launch_bounds__(256) void rsqrt_kernel(const float* __restrict__ deg,
                                                    float* __restrict__ dinv, int N) {
  int v = blockIdx.x * 256 + threadIdx.x;
  if (v < N) dinv[v] = 1.0f / sqrtf(deg[v] + 1.0f);
}

__global__ __launch_bounds__(256) void rsqrt2_kernel(
    const float* __restrict__ a, const float* __restrict__ b,
    float* __restrict__ oa, float* __restrict__ ob, int N) {
  int v = blockIdx.x * 256 + threadIdx.x;
  if (v < N) {
    oa[v] = 1.0f / sqrtf(a[v] + 1.0f);
    ob[v] = 1.0f / sqrtf(b[v] + 1.0f);
  }
}

// ---------------- aggregation: 4 groups x 16 lanes, 4 edges in flight ----------------
#define AGG_BODY(WEXPR)                                                        \
  for (int s = s0; s < s1; s += 4) {                                           \
    int e = s + g;                                                             \
    int src = v; float w = 0.f;                                                \
    if (e < s1) { src = csr_src[e]; WEXPR; }                                   \
    uint4 u = T[(size_t)src * 16 + li];                                        \
    acc[0] += w * bflo(u.x); acc[1] += w * bfhi(u.x);                          \
    acc[2] += w * bflo(u.y); acc[3] += w * bfhi(u.y);                          \
    acc[4] += w * bflo(u.z); acc[5] += w * bfhi(u.z);                          \
    acc[6] += w * bflo(u.w); acc[7] += w * bfhi(u.w);                          \
  }

__global__ __launch_bounds__(256) void agg_kernel(
    const u16* __restrict__ t, const int* __restrict__ csr_src,
    const int* __restrict__ csr_eid, const float* __restrict__ att,
    const int* __restrict__ off, const float* __restrict__ dinv,
    const float* __restrict__ bias, u16* __restrict__ out, int N) {
  int v = blockIdx.x * 4 + (threadIdx.x >> 6);
  if (v >= N) return;
  int lane = threadIdx.x & 63;
  int g = lane >> 4, li = lane & 15;
  const uint4* T = (const uint4*)t;
  float dv = dinv[v];
  float acc[8] = {0.f, 0.f, 0.f, 0.f, 0.f, 0.f, 0.f, 0.f};
  if (g == 0) {
    uint4 u = T[(size_t)v * 16 + li];
    float w0 = dv * dv;
    acc[0] = w0 * bflo(u.x); acc[1] = w0 * bfhi(u.x);
    acc[2] = w0 * bflo(u.y); acc[3] = w0 * bfhi(u.y);
    acc[4] = w0 * bflo(u.z); acc[5] = w0 * bfhi(u.z);
    acc[6] = w0 * bflo(u.w); acc[7] = w0 * bfhi(u.w);
  }
  int s0 = off[v], s1 = off[v + 1];
  if (att) {
#pragma unroll 2
    AGG_BODY(w = dinv[src] * dv * att[csr_eid[e]])
  } else {
#pragma unroll 2
    AGG_BODY(w = dinv[src] * dv)
  }
#pragma unroll
  for (int j = 0; j < 8; j++) {
    acc[j] += __shfl_xor(acc[j], 16);
    acc[j] += __shfl_xor(acc[j], 32);
  }
  if (g == 0) {
    float o[8];
#pragma unroll
    for (int j = 0; j < 8; j++) o[j] = fmaxf(acc[j] + bias[li * 8 + j], 0.f);
    uint4 w4;
    w4.x = pack2(o[0], o[1]); w4.y = pack2(o[2], o[3]);
    w4.z = pack2(o[4], o[5]); w4.w = pack2(o[6], o[7]);
    ((uint4*)out)[(size_t)v * 16 + li] = w4;
  }
}

// ---------------- node attention + edge-att p,q factors ----------------
__global__ __launch_bounds__(256) void natt_kernel(
    const u16* __restrict__ h, int N,
    const float* __restrict__ W_na, const float* __restrict__ b_na,
    const float* __restrict__ W_ea,
    float* __restrict__ na0, float* __restrict__ na1,
    float* __restrict__ p0, float* __restrict__ p1,
    float* __restrict__ q0, float* __restrict__ q1) {
  int n = blockIdx.x * 256 + threadIdx.x;
  if (n >= N) return;
  float sa0 = 0, sa1 = 0, sp0 = 0, sp1 = 0, sq0 = 0, sq1 = 0;
  const uint2* hr = (const uint2*)(h + (size_t)n * H);
  for (int c = 0; c < 32; c++) {
    uint2 u = hr[c];
    float v0 = bflo(u.x), v1 = bfhi(u.x), v2 = bflo(u.y), v3 = bfhi(u.y);
    int k = c * 4;
    sa0 += v0 * W_na[k * 2] + v1 * W_na[k * 2 + 2] + v2 * W_na[k * 2 + 4] + v3 * W_na[k * 2 + 6];
    sa1 += v0 * W_na[k * 2 + 1] + v1 * W_na[k * 2 + 3] + v2 * W_na[k * 2 + 5] + v3 * W_na[k * 2 + 7];
    sp0 += v0 * W_ea[k * 2] + v1 * W_ea[k * 2 + 2] + v2 * W_ea[k * 2 + 4] + v3 * W_ea[k * 2 + 6];
    sp1 += v0 * W_ea[k * 2 + 1] + v1 * W_ea[k * 2 + 3] + v2 * W_ea[k * 2 + 5] + v3 * W_ea[k * 2 + 7];
    sq0 += v0 * W_ea[(H + k) * 2] + v1 * W_ea[(H + k) * 2 + 2] + v2 * W_ea[(H + k) * 2 + 4] + v3 * W_ea[(H + k) * 2 + 6];
    sq1 += v0 * W_ea[(H + k) * 2 + 1] + v1 * W_ea[(H + k) * 2 + 3] + v2 * W_ea[(H + k) * 2 + 5] + v3 * W_ea[(H + k) * 2 + 7];
  }
  sa0 += b_na[0]; sa1 += b_na[1];
  float m = fmaxf(sa0, sa1);
  float e0 = expf(sa0 - m), e1 = expf(sa1 - m);
  float inv = 1.f / (e0 + e1);
  na0[n] = e0 * inv; na1[n] = e1 * inv;
  p0[n] = sp0; p1[n] = sp1; q0[n] = sq0; q1[n] = sq1;
}

// ---------------- xc_pre = na0*h, xo_pre = na1*h ----------------
__global__ __launch_bounds__(256) void xpre_kernel(
    const u16* __restrict__ h, const float* __restrict__ na0,
    const float* __restrict__ na1, u16* __restrict__ xc, u16* __restrict__ xo, int n4) {
  int i = blockIdx.x * 256 + threadIdx.x;
  if (i >= n4) return;
  int n = i >> 5;
  uint2 u = ((const uint2*)h)[i];
  float v0 = bflo(u.x), v1 = bfhi(u.x), v2 = bflo(u.y), v3 = bfhi(u.y);
  float a = na0[n], b = na1[n];
  ((uint2*)xc)[i] = make_uint2(pack2(v0 * a, v1 * a), pack2(v2 * a, v3 * a));
  ((uint2*)xo)[i] = make_uint2(pack2(v0 * b, v1 * b), pack2(v2 * b, v3 * b));
}

// ---------------- edge attention + weighted degree ----------------
__global__ __launch_bounds__(256) void eatt_kernel(
    const int* __restrict__ row, const int* __restrict__ col, int E,
    const float* __restrict__ p0, const float* __restrict__ p1,
    const float* __restrict__ q0, const float* __restrict__ q1,
    const float* __restrict__ b_ea,
    float* __restrict__ att0, float* __restrict__ att1,
    float* __restrict__ degc, float* __restrict__ dego) {
  int e = blockIdx.x * 256 + threadIdx.x;
  if (e >= E) return;
  int r = row[e], c = col[e];
  float l0 = p0[r] + q0[c] + b_ea[0];
  float l1 = p1[r] + q1[c] + b_ea[1];
  float m = fmaxf(l0, l1);
  float e0 = expf(l0 - m), e1 = expf(l1 - m);
  float inv = 1.f / (e0 + e1);
  float a0 = e0 * inv, a1 = e1 * inv;
  att0[e] = a0; att1[e] = a1;
  atomicAdd(&degc[r], a0);
  atomicAdd(&dego[r], a1);
}

// ---------------- h_co = xc[perm] + xo ----------------
__global__ __launch_bounds__(256) void permadd_kernel(
    const u16* __restrict__ xc, const u16* __restrict__ xo,
    const int* __restrict__ perm, u16* __restrict__ out, int n4) {
  int i = blockIdx.x * 256 + threadIdx.x;
  if (i >= n4) return;
  int n = i >> 5, k = i & 31;
  int p = perm[n];
  uint2 a = ((const uint2*)xc)[(size_t)p * 32 + k];
  uint2 b = ((const uint2*)xo)[i];
  ((uint2*)out)[i] = make_uint2(pack2(bflo(a.x) + bflo(b.x), bfhi(a.x) + bfhi(b.x)),
                                pack2(bflo(a.y) + bflo(b.y), bfhi(a.y) + bfhi(b.y)));
}

// ---------------- fc2 [N,128]@[128,10] + log_softmax ----------------
__global__ __launch_bounds__(256) void fc2_kernel(
    const u16* __restrict__ z, const float* __restrict__ W2,
    const float* __restrict__ c2, float* __restrict__ outp, int N) {
  int n = blockIdx.x * 256 + threadIdx.x;
  if (n >= N) return;
  float acc[NCLS];
#pragma unroll
  for (int c = 0; c < NCLS; c++) acc[c] = c2[c];
  const uint2* zr = (const uint2*)(z + (size_t)n * H);
  for (int c4 = 0; c4 < 32; c4++) {
    uint2 u = zr[c4];
    float v[4] = {bflo(u.x), bfhi(u.x), bflo(u.y), bfhi(u.y)};
    int k = c4 * 4;
#pragma unroll
    for (int j = 0; j < 4; j++)
#pragma unroll
      for (int c = 0; c < NCLS; c++) acc[c] += v[j] * W2[(k + j) * NCLS + c];
  }
  float m = acc[0];
#pragma unroll
  for (int c = 1; c < NCLS; c++) m = fmaxf(m, acc[c]);
  float s = 0.f;
#pragma unroll
  for (int c = 0; c < NCLS; c++) s += expf(acc[c] - m);
  float lse = logf(s) + m;
#pragma unroll
  for (int c = 0; c < NCLS; c++) outp[(size_t)n * NCLS + c] = acc[c] - lse;
}

// =============================================================================
extern "C" void kernel_launch(void* const* d_in, const int* in_sizes, int n_in,
                              void* d_out, int out_size, void* d_ws, size_t ws_size,
                              hipStream_t stream) {
  const int N = in_sizes[0] / H;
  const int E = in_sizes[1] / 2;
  const float* x = (const float*)d_in[0];
  const int* ei = (const int*)d_in[1];
  const int* row = ei;
  const int* col = ei + E;
  const int* perm = (const int*)d_in[2];
  const float* W_feat = (const float*)d_in[3];
  const float* b_feat = (const float*)d_in[4];
  const float* W_convs = (const float*)d_in[5];
  const float* b_convs = (const float*)d_in[6];
  const float* W_ea = (const float*)d_in[7];
  const float* b_ea = (const float*)d_in[8];
  const float* W_na = (const float*)d_in[9];
  const float* b_na = (const float*)d_in[10];
  const float* W_ctx = (const float*)d_in[11];
  const float* b_ctx = (const float*)d_in[12];
  const float* W_obj = (const float*)d_in[13];
  const float* b_obj = (const float*)d_in[14];
  const float* W_fc1 = (const float*)d_in[15];
  const float* b_fc1 = (const float*)d_in[16];
  const float* W_fc2 = (const float*)d_in[17];
  const float* b_fc2 = (const float*)d_in[18];
  float* out = (float*)d_out;

  // ---------- workspace carve ----------
  char* base = (char*)d_ws;
  size_t off_b = 0;
  auto alloc = [&](size_t bytes) -> void* {
    void* p = base + off_b;
    off_b = (off_b + bytes + 255) & ~(size_t)255;
    return p;
  };
  size_t NB2 = (size_t)N * H * sizeof(u16);
  u16* bufA = (u16*)alloc(NB2);
  u16* bufB = (u16*)alloc(NB2);
  u16* bufC = (u16*)alloc(NB2);
  u16* bufD = (u16*)alloc(NB2);
  u16* xbf = (u16*)alloc(NB2);
  // zero-region: cnt, deg, degc, dego (one memset)
  int* cnt = (int*)alloc(4 * (size_t)N * 4);
  float* deg = (float*)(cnt + N);
  float* degc = (float*)(cnt + 2 * (size_t)N);
  float* dego = (float*)(cnt + 3 * (size_t)N);
  float* stp = (float*)alloc((size_t)CS_BLOCKS * 256 * 4);  // colstats partials
  int* off = (int*)alloc(((size_t)N + 1) * 4);
  int* cur = (int*)alloc((size_t)N * 4);
  float* dinv = (float*)alloc((size_t)N * 4);
  float* dinvc = (float*)alloc((size_t)N * 4);
  float* dinvo = (float*)alloc((size_t)N * 4);
  float* na0 = (float*)alloc((size_t)N * 4);
  float* na1 = (float*)alloc((size_t)N * 4);
  float* p0 = (float*)alloc((size_t)N * 4);
  float* p1 = (float*)alloc((size_t)N * 4);
  float* q0 = (float*)alloc((size_t)N * 4);
  float* q1 = (float*)alloc((size_t)N * 4);
  int* partial = (int*)alloc(256 * 4);
  int* blockoff = (int*)alloc(256 * 4);
  u16* Wt = (u16*)alloc((size_t)H * H * 2);
  float* cf = (float*)alloc(H * 4);
  float* W2f = (float*)alloc((size_t)H * NCLS * 4);
  float* c2f = (float*)alloc(16 * 4);
  float* att0 = (float*)alloc((size_t)E * 4);
  float* att1 = (float*)alloc((size_t)E * 4);
  int* csr_src = (int*)alloc((size_t)E * 4);
  int* csr_eid = (int*)alloc((size_t)E * 4);

  const float invN = 1.0f / (float)N;
  const int gN = (N + 255) / 256;
  const int gE = (E + 255) / 256;
  const int SB = (N + 255) / 256;
  const int gG = (N + 63) / 64;
  const int n4 = N * 32;
  const int gV = (n4 + 255) / 256;
  const int gAgg = (N + 3) / 4;

#define STATS(SRC) colstats_kernel<<<CS_BLOCKS, 256, 0, stream>>>((SRC), N, stp);

  // ---------- one memset for contended accumulators ----------
  hipMemsetAsync(cnt, 0, 4 * (size_t)N * 4, stream);

  // ---------- CSR + degrees ----------
  hist_kernel<<<gE, 256, 0, stream>>>(row, col, E, cnt, deg);
  scanA_kernel<<<SB, 256, 0, stream>>>(cnt, N, partial);
  scanB_kernel<<<1, 256, 0, stream>>>(partial, SB, blockoff);
  scanC_kernel<<<SB, 256, 0, stream>>>(cnt, N, blockoff, off, cur, E);
  place_kernel<<<gE, 256, 0, stream>>>(row, col, E, cur, csr_src, csr_eid);
  rsqrt_kernel<<<gN, 256, 0, stream>>>(deg, dinv, N);

  // ---------- feature layer ----------
  xcvt_kernel<<<gV, 256, 0, stream>>>(x, xbf, n4);
  STATS(xbf);
  fold_kernel<<<H, H, 0, stream>>>(stp, CS_BLOCKS, W_feat, b_feat, invN, Wt, cf);
  gemm_kernel<<<gG, 256, 0, stream>>>(xbf, Wt, cf, bufA, N, 1);

  // ---------- 3 GCN convs ----------
  for (int i = 0; i < 3; ++i) {
    STATS(bufA);
    fold_kernel<<<H, H, 0, stream>>>(stp, CS_BLOCKS, W_convs + (size_t)i * H * H,
                                     nullptr, invN, Wt, cf);
    gemm_kernel<<<gG, 256, 0, stream>>>(bufA, Wt, cf, bufC, N, 0);
    agg_kernel<<<gAgg, 256, 0, stream>>>(bufC, csr_src, csr_eid, nullptr, off, dinv,
                                         b_convs + (size_t)i * H, bufA, N);
  }

  // ---------- attention ----------
  natt_kernel<<<gN, 256, 0, stream>>>(bufA, N, W_na, b_na, W_ea, na0, na1, p0, p1, q0, q1);
  eatt_kernel<<<gE, 256, 0, stream>>>(row, col, E, p0, p1, q0, q1, b_ea, att0, att1,
                                      degc, dego);
  rsqrt2_kernel<<<gN, 256, 0, stream>>>(degc, dego, dinvc, dinvo, N);
  xpre_kernel<<<gV, 256, 0, stream>>>(bufA, na0, na1, bufB, bufC, n4);

  // ---------- ctx conv (uses stats of bufB before bufC chain runs) ----------
  STATS(bufB);
  fold_kernel<<<H, H, 0, stream>>>(stp, CS_BLOCKS, W_ctx, nullptr, invN, Wt, cf);
  gemm_kernel<<<gG, 256, 0, stream>>>(bufB, Wt, cf, bufD, N, 0);
  agg_kernel<<<gAgg, 256, 0, stream>>>(bufD, csr_src, csr_eid, att0, off, dinvc, b_ctx,
                                       bufB, N);  // xc in B

  // ---------- obj conv ----------
  STATS(bufC);
  fold_kernel<<<H, H, 0, stream>>>(stp, CS_BLOCKS, W_obj, nullptr, invN, Wt, cf);
  gemm_kernel<<<gG, 256, 0, stream>>>(bufC, Wt, cf, bufD, N, 0);
  agg_kernel<<<gAgg, 256, 0, stream>>>(bufD, csr_src, csr_eid, att1, off, dinvo, b_obj,
                                       bufA, N);  // xo in A

  // ---------- h_co = xc[perm] + xo ----------
  permadd_kernel<<<gV, 256, 0, stream>>>(bufB, bufA, perm, bufD, n4);

  // ---------- 3 readouts ----------
  const u16* Xin[3] = {bufB, bufA, bufD};
  for (int j = 0; j < 3; ++j) {
    STATS(Xin[j]);
    fold_kernel<<<H, H, 0, stream>>>(stp, CS_BLOCKS, W_fc1 + (size_t)j * H * H,
                                     b_fc1 + (size_t)j * H, invN, Wt, cf);
    gemm_kernel<<<gG, 256, 0, stream>>>(Xin[j], Wt, cf, bufC, N, 1);
    STATS(bufC);
    fold10_kernel<<<NCLS, H, 0, stream>>>(stp, CS_BLOCKS, W_fc2 + (size_t)j * H * NCLS,
                                          b_fc2 + (size_t)j * NCLS, invN, W2f, c2f);
    fc2_kernel<<<gN, 256, 0, stream>>>(bufC, W2f, c2f, out + (size_t)j * N * NCLS, N);
  }
#undef STATS
}

// Round 5
// 1533.099 us; speedup vs baseline: 1.6455x; 1.0707x over previous
//
#include <hip/hip_runtime.h>
#include <math.h>

#define H 128
#define NCLS 10
#define EPS 1e-5f
#define BN_BETA 1e-4f
#define CS_BLOCKS 256  // colstats stage-1 blocks (= partial rows)

typedef unsigned short u16;
typedef unsigned int u32;
typedef __attribute__((ext_vector_type(8))) short short8;
typedef __attribute__((ext_vector_type(4))) float floatx4;

// ---- bf16 helpers (bit ops; RNE) ----
__device__ inline float bflo(u32 u) { union { u32 i; float f; } a; a.i = u << 16; return a.f; }
__device__ inline float bfhi(u32 u) { union { u32 i; float f; } a; a.i = u & 0xffff0000u; return a.f; }
__device__ inline u16 f2bf(float f) {
  union { float f; u32 i; } v; v.f = f;
  return (u16)((v.i + 0x7fff + ((v.i >> 16) & 1)) >> 16);
}
__device__ inline u32 pack2(float a, float b) { return (u32)f2bf(a) | ((u32)f2bf(b) << 16); }

// ---------------- x fp32 -> bf16 ----------------
__global__ __launch_bounds__(256) void xcvt_kernel(const float* __restrict__ x,
                                                   u16* __restrict__ xb, int n4) {
  int i = blockIdx.x * 256 + threadIdx.x;
  if (i >= n4) return;
  float4 v = ((const float4*)x)[i];
  ((uint2*)xb)[i] = make_uint2(pack2(v.x, v.y), pack2(v.z, v.w));
}

// ---------------- column stats stage 1: NO atomics, per-block partial row ----
__global__ __launch_bounds__(256) void colstats_kernel(
    const u16* __restrict__ X, int N, float* __restrict__ partial) {
  int tid = threadIdx.x;
  int li = tid & 15;   // 16B chunk within row (8 cols)
  int rg = tid >> 4;   // row group 0..15
  int wave = tid >> 6, lane = tid & 63;
  const uint4* T = (const uint4*)X;
  float s[8] = {0, 0, 0, 0, 0, 0, 0, 0}, q[8] = {0, 0, 0, 0, 0, 0, 0, 0};
  for (int r = blockIdx.x * 16 + rg; r < N; r += gridDim.x * 16) {
    uint4 u = T[(size_t)r * 16 + li];
    float f[8] = {bflo(u.x), bfhi(u.x), bflo(u.y), bfhi(u.y),
                  bflo(u.z), bfhi(u.z), bflo(u.w), bfhi(u.w)};
#pragma unroll
    for (int j = 0; j < 8; j++) { s[j] += f[j]; q[j] += f[j] * f[j]; }
  }
#pragma unroll
  for (int j = 0; j < 8; j++) {
    s[j] += __shfl_xor(s[j], 16); s[j] += __shfl_xor(s[j], 32);
    q[j] += __shfl_xor(q[j], 16); q[j] += __shfl_xor(q[j], 32);
  }
  __shared__ float sm[4][256];
  if ((lane & 48) == 0) {
#pragma unroll
    for (int j = 0; j < 8; j++) {
      sm[wave][li * 8 + j] = s[j];
      sm[wave][128 + li * 8 + j] = q[j];
    }
  }
  __syncthreads();
  float v = sm[0][tid] + sm[1][tid] + sm[2][tid] + sm[3][tid];
  partial[(size_t)blockIdx.x * 256 + tid] = v;
}

// ---------------- fold: reduce partials + BN-fold into W (bf16, transposed) ----
__global__ __launch_bounds__(128) void fold_kernel(
    const float* __restrict__ partial, int nb,
    const float* __restrict__ W, const float* __restrict__ bias, float invN,
    u16* __restrict__ Wt_bf, float* __restrict__ cout_) {
  int k = blockIdx.x;
  int f = threadIdx.x;
  float su = 0.f, sq = 0.f;
  for (int b = 0; b < nb; b++) {
    su += partial[(size_t)b * 256 + f];
    sq += partial[(size_t)b * 256 + 128 + f];
  }
  float mu = su * invN;
  float var = sq * invN - mu * mu;
  float s = 1.0f / sqrtf(fmaxf(var, 0.f) + EPS);
  float w = W[(size_t)f * H + k];
  Wt_bf[(size_t)k * H + f] = f2bf(s * w);
  __shared__ float red[H];
  red[f] = (BN_BETA - mu * s) * w;
  __syncthreads();
  for (int o = 64; o > 0; o >>= 1) {
    if (f < o) red[f] += red[f + o];
    __syncthreads();
  }
  if (f == 0) cout_[k] = red[0] + (bias ? bias[k] : 0.f);
}

// ---------------- fold for fc2 (Kout=10), fp32 out ----------------
__global__ __launch_bounds__(128) void fold10_kernel(
    const float* __restrict__ partial, int nb,
    const float* __restrict__ W, const float* __restrict__ bias, float invN,
    float* __restrict__ Wout, float* __restrict__ cout_) {
  int k = blockIdx.x;
  int f = threadIdx.x;
  float su = 0.f, sq = 0.f;
  for (int b = 0; b < nb; b++) {
    su += partial[(size_t)b * 256 + f];
    sq += partial[(size_t)b * 256 + 128 + f];
  }
  float mu = su * invN;
  float var = sq * invN - mu * mu;
  float s = 1.0f / sqrtf(fmaxf(var, 0.f) + EPS);
  float w = W[(size_t)f * NCLS + k];
  Wout[(size_t)f * NCLS + k] = s * w;
  __shared__ float red[H];
  red[f] = (BN_BETA - mu * s) * w;
  __syncthreads();
  for (int o = 64; o > 0; o >>= 1) {
    if (f < o) red[f] += red[f + o];
    __syncthreads();
  }
  if (f == 0) cout_[k] = red[0] + bias[k];
}

// ---------------- bf16 MFMA GEMM: C[N,128] = A[N,128] @ Wt^T + c ----------------
__global__ __launch_bounds__(256) void gemm_kernel(
    const u16* __restrict__ A, const u16* __restrict__ Bt,
    const float* __restrict__ bias, u16* __restrict__ C, int N, int relu) {
  int tid = threadIdx.x;
  int wave = tid >> 6, lane = tid & 63;
  int l15 = lane & 15, quad = lane >> 4;
  int row0 = (blockIdx.x * 4 + wave) * 16;
  if (row0 >= N) return;
  int arow = row0 + l15;
  short8 a[4];
  short8 z8 = {0, 0, 0, 0, 0, 0, 0, 0};
#pragma unroll
  for (int k4 = 0; k4 < 4; k4++)
    a[k4] = (arow < N) ? *(const short8*)(A + (size_t)arow * H + k4 * 32 + quad * 8) : z8;
#pragma unroll
  for (int nt = 0; nt < 8; nt++) {
    floatx4 acc = {0.f, 0.f, 0.f, 0.f};
    const u16* bp = Bt + (size_t)(nt * 16 + l15) * H + quad * 8;
#pragma unroll
    for (int k4 = 0; k4 < 4; k4++) {
      short8 b = *(const short8*)(bp + k4 * 32);
      acc = __builtin_amdgcn_mfma_f32_16x16x32_bf16(a[k4], b, acc, 0, 0, 0);
    }
    int col = nt * 16 + l15;
    float bs = bias[col];
#pragma unroll
    for (int r = 0; r < 4; r++) {
      int row = row0 + quad * 4 + r;
      if (row < N) {
        float v = acc[r] + bs;
        if (relu) v = fmaxf(v, 0.f);
        C[(size_t)row * H + col] = f2bf(v);
      }
    }
  }
}

// ---------------- CSR build ----------------
__global__ __launch_bounds__(256) void hist_kernel(
    const int* __restrict__ row, const int* __restrict__ col, int E,
    int* __restrict__ cnt, float* __restrict__ deg) {
  int e = blockIdx.x * 256 + threadIdx.x;
  if (e < E) {
    atomicAdd(&cnt[col[e]], 1);
    atomicAdd(&deg[row[e]], 1.0f);
  }
}

__global__ __launch_bounds__(256) void scanA_kernel(const int* __restrict__ cnt, int N,
                                                    int* __restrict__ partial) {
  __shared__ int sd[256];
  int i = blockIdx.x * 256 + threadIdx.x;
  sd[threadIdx.x] = (i < N) ? cnt[i] : 0;
  __syncthreads();
  for (int o = 128; o > 0; o >>= 1) {
    if (threadIdx.x < o) sd[threadIdx.x] += sd[threadIdx.x + o];
    __syncthreads();
  }
  if (threadIdx.x == 0) partial[blockIdx.x] = sd[0];
}

__global__ __launch_bounds__(256) void scanB_kernel(const int* __restrict__ partial, int nb,
                                                    int* __restrict__ blockoff) {
  __shared__ int sd[256];
  int t = threadIdx.x;
  int v = (t < nb) ? partial[t] : 0;
  sd[t] = v;
  __syncthreads();
  for (int o = 1; o < 256; o <<= 1) {
    int x = (t >= o) ? sd[t - o] : 0;
    __syncthreads();
    sd[t] += x;
    __syncthreads();
  }
  blockoff[t] = sd[t] - v;
}

__global__ __launch_bounds__(256) void scanC_kernel(
    const int* __restrict__ cnt, int N, const int* __restrict__ blockoff,
    int* __restrict__ off, int* __restrict__ cur, int E) {
  __shared__ int sd[256];
  int t = threadIdx.x;
  int i = blockIdx.x * 256 + t;
  int v = (i < N) ? cnt[i] : 0;
  sd[t] = v;
  __syncthreads();
  for (int o = 1; o < 256; o <<= 1) {
    int x = (t >= o) ? sd[t - o] : 0;
    __syncthreads();
    sd[t] += x;
    __syncthreads();
  }
  if (i < N) {
    int ex = blockoff[blockIdx.x] + sd[t] - v;
    off[i] = ex;
    cur[i] = ex;
  }
  if (i == 0) off[N] = E;
}

// place: build csr_src + inverse map slot_of[e]
__global__ __launch_bounds__(256) void place_kernel(
    const int* __restrict__ row, const int* __restrict__ col, int E,
    int* __restrict__ cur, int* __restrict__ csr_src, int* __restrict__ slot_of) {
  int e = blockIdx.x * 256 + threadIdx.x;
  if (e < E) {
    int slot = atomicAdd(&cur[col[e]], 1);
    csr_src[slot] = row[e];
    slot_of[e] = slot;
  }
}

__global__ __launch_bounds__(256) void rsqrt_kernel(const float* __restrict__ deg,
                                                    float* __restrict__ dinv, int N) {
  int v = blockIdx.x * 256 + threadIdx.x;
  if (v < N) dinv[v] = 1.0f / sqrtf(deg[v] + 1.0f);
}

// dinvc = rsqrt(degc+1); dinvo = rsqrt(deg-degc+1)   [att0+att1=1 => dego=deg-degc]
__global__ __launch_bounds__(256) void rsqrt2_kernel(
    const float* __restrict__ deg, const float* __restrict__ degc,
    float* __restrict__ dinvc, float* __restrict__ dinvo, int N) {
  int v = blockIdx.x * 256 + threadIdx.x;
  if (v < N) {
    float dc = degc[v];
    dinvc[v] = 1.0f / sqrtf(dc + 1.0f);
    dinvo[v] = 1.0f / sqrtf(deg[v] - dc + 1.0f);
  }
}

// ---------------- per-slot weight precompute (streaming, latency-tolerant) ----
__global__ __launch_bounds__(256) void wnorm_kernel(
    const int* __restrict__ csr_src, const float* __restrict__ dinv,
    float* __restrict__ wn, int E) {
  int i = blockIdx.x * 256 + threadIdx.x;
  if (i < E) wn[i] = dinv[csr_src[i]];
}

__global__ __launch_bounds__(256) void wa_kernel(
    const int* __restrict__ csr_src, const float* __restrict__ att0s,
    const float* __restrict__ dinvc, const float* __restrict__ dinvo,
    float* __restrict__ wa0, float* __restrict__ wa1, int E) {
  int i = blockIdx.x * 256 + threadIdx.x;
  if (i < E) {
    int s = csr_src[i];
    float a0 = att0s[i];
    wa0[i] = a0 * dinvc[s];
    wa1[i] = (1.0f - a0) * dinvo[s];
  }
}

// ---------------- aggregation: 4 groups x 16 lanes, 16 gathers in flight ----------------
__global__ __launch_bounds__(256) void agg_kernel(
    const u16* __restrict__ t, const int* __restrict__ csr_src,
    const float* __restrict__ wseg, const int* __restrict__ off,
    const float* __restrict__ dinv, const float* __restrict__ bias,
    u16* __restrict__ out, int N) {
  int v = blockIdx.x * 4 + (threadIdx.x >> 6);
  if (v >= N) return;
  int lane = threadIdx.x & 63;
  int g = lane >> 4, li = lane & 15;
  const uint4* T = (const uint4*)t;
  float dv = dinv[v];
  float acc[8] = {0.f, 0.f, 0.f, 0.f, 0.f, 0.f, 0.f, 0.f};
  if (g == 0) {
    uint4 u = T[(size_t)v * 16 + li];
    float w0 = dv * dv;
    acc[0] = w0 * bflo(u.x); acc[1] = w0 * bfhi(u.x);
    acc[2] = w0 * bflo(u.y); acc[3] = w0 * bfhi(u.y);
    acc[4] = w0 * bflo(u.z); acc[5] = w0 * bfhi(u.z);
    acc[6] = w0 * bflo(u.w); acc[7] = w0 * bfhi(u.w);
  }
  int s0 = off[v], s1 = off[v + 1];
#define ACC8(U, W)                                                \
  acc[0] += (W) * bflo(U.x); acc[1] += (W) * bfhi(U.x);           \
  acc[2] += (W) * bflo(U.y); acc[3] += (W) * bfhi(U.y);           \
  acc[4] += (W) * bflo(U.z); acc[5] += (W) * bfhi(U.z);           \
  acc[6] += (W) * bflo(U.w); acc[7] += (W) * bfhi(U.w);
  for (int s = s0; s < s1; s += 16) {
    int e0 = s + g, e1 = e0 + 4, e2 = e0 + 8, e3 = e0 + 12;
    int r0 = v, r1 = v, r2 = v, r3 = v;
    float w0 = 0.f, w1 = 0.f, w2 = 0.f, w3 = 0.f;
    if (e0 < s1) { r0 = csr_src[e0]; w0 = wseg[e0]; }
    if (e1 < s1) { r1 = csr_src[e1]; w1 = wseg[e1]; }
    if (e2 < s1) { r2 = csr_src[e2]; w2 = wseg[e2]; }
    if (e3 < s1) { r3 = csr_src[e3]; w3 = wseg[e3]; }
    uint4 u0 = T[(size_t)r0 * 16 + li];
    uint4 u1 = T[(size_t)r1 * 16 + li];
    uint4 u2 = T[(size_t)r2 * 16 + li];
    uint4 u3 = T[(size_t)r3 * 16 + li];
    w0 *= dv; w1 *= dv; w2 *= dv; w3 *= dv;
    ACC8(u0, w0) ACC8(u1, w1) ACC8(u2, w2) ACC8(u3, w3)
  }
#undef ACC8
#pragma unroll
  for (int j = 0; j < 8; j++) {
    acc[j] += __shfl_xor(acc[j], 16);
    acc[j] += __shfl_xor(acc[j], 32);
  }
  if (g == 0) {
    float o[8];
#pragma unroll
    for (int j = 0; j < 8; j++) o[j] = fmaxf(acc[j] + bias[li * 8 + j], 0.f);
    uint4 w4;
    w4.x = pack2(o[0], o[1]); w4.y = pack2(o[2], o[3]);
    w4.z = pack2(o[4], o[5]); w4.w = pack2(o[6], o[7]);
    ((uint4*)out)[(size_t)v * 16 + li] = w4;
  }
}

// ---------------- node attention + edge-att p,q factors (packed float2) ------
__global__ __launch_bounds__(256) void natt_kernel(
    const u16* __restrict__ h, int N,
    const float* __restrict__ W_na, const float* __restrict__ b_na,
    const float* __restrict__ W_ea,
    float2* __restrict__ na01, float2* __restrict__ p01, float2* __restrict__ q01) {
  int n = blockIdx.x * 256 + threadIdx.x;
  if (n >= N) return;
  float sa0 = 0, sa1 = 0, sp0 = 0, sp1 = 0, sq0 = 0, sq1 = 0;
  const uint2* hr = (const uint2*)(h + (size_t)n * H);
  for (int c = 0; c < 32; c++) {
    uint2 u = hr[c];
    float v0 = bflo(u.x), v1 = bfhi(u.x), v2 = bflo(u.y), v3 = bfhi(u.y);
    int k = c * 4;
    sa0 += v0 * W_na[k * 2] + v1 * W_na[k * 2 + 2] + v2 * W_na[k * 2 + 4] + v3 * W_na[k * 2 + 6];
    sa1 += v0 * W_na[k * 2 + 1] + v1 * W_na[k * 2 + 3] + v2 * W_na[k * 2 + 5] + v3 * W_na[k * 2 + 7];
    sp0 += v0 * W_ea[k * 2] + v1 * W_ea[k * 2 + 2] + v2 * W_ea[k * 2 + 4] + v3 * W_ea[k * 2 + 6];
    sp1 += v0 * W_ea[k * 2 + 1] + v1 * W_ea[k * 2 + 3] + v2 * W_ea[k * 2 + 5] + v3 * W_ea[k * 2 + 7];
    sq0 += v0 * W_ea[(H + k) * 2] + v1 * W_ea[(H + k) * 2 + 2] + v2 * W_ea[(H + k) * 2 + 4] + v3 * W_ea[(H + k) * 2 + 6];
    sq1 += v0 * W_ea[(H + k) * 2 + 1] + v1 * W_ea[(H + k) * 2 + 3] + v2 * W_ea[(H + k) * 2 + 5] + v3 * W_ea[(H + k) * 2 + 7];
  }
  sa0 += b_na[0]; sa1 += b_na[1];
  float m = fmaxf(sa0, sa1);
  float e0 = expf(sa0 - m), e1 = expf(sa1 - m);
  float inv = 1.f / (e0 + e1);
  na01[n] = make_float2(e0 * inv, e1 * inv);
  p01[n] = make_float2(sp0, sp1);
  q01[n] = make_float2(sq0, sq1);
}

// ---------------- xc_pre = na0*h, xo_pre = na1*h ----------------
__global__ __launch_bounds__(256) void xpre_kernel(
    const u16* __restrict__ h, const float2* __restrict__ na01,
    u16* __restrict__ xc, u16* __restrict__ xo, int n4) {
  int i = blockIdx.x * 256 + threadIdx.x;
  if (i >= n4) return;
  int n = i >> 5;
  uint2 u = ((const uint2*)h)[i];
  float v0 = bflo(u.x), v1 = bfhi(u.x), v2 = bflo(u.y), v3 = bfhi(u.y);
  float2 ab = na01[n];
  float a = ab.x, b = ab.y;
  ((uint2*)xc)[i] = make_uint2(pack2(v0 * a, v1 * a), pack2(v2 * a, v3 * a));
  ((uint2*)xo)[i] = make_uint2(pack2(v0 * b, v1 * b), pack2(v2 * b, v3 * b));
}

// ---------------- edge attention -> CSR-order att0 + degc (1 atomic/edge) ----
__global__ __launch_bounds__(256) void eatt_kernel(
    const int* __restrict__ row, const int* __restrict__ col, int E,
    const float2* __restrict__ p01, const float2* __restrict__ q01,
    const float* __restrict__ b_ea, const int* __restrict__ slot_of,
    float* __restrict__ att0s, float* __restrict__ degc) {
  int e = blockIdx.x * 256 + threadIdx.x;
  if (e >= E) return;
  int r = row[e], c = col[e];
  float2 p = p01[r], q = q01[c];
  float l0 = p.x + q.x + b_ea[0];
  float l1 = p.y + q.y + b_ea[1];
  float a0 = 1.0f / (1.0f + expf(l1 - l0));  // softmax over 2 logits
  att0s[slot_of[e]] = a0;
  atomicAdd(&degc[r], a0);
}

// ---------------- h_co = xc[perm] + xo ----------------
__global__ __launch_bounds__(256) void permadd_kernel(
    const u16* __restrict__ xc, const u16* __restrict__ xo,
    const int* __restrict__ perm, u16* __restrict__ out, int n4) {
  int i = blockIdx.x * 256 + threadIdx.x;
  if (i >= n4) return;
  int n = i >> 5, k = i & 31;
  int p = perm[n];
  uint2 a = ((const uint2*)xc)[(size_t)p * 32 + k];
  uint2 b = ((const uint2*)xo)[i];
  ((uint2*)out)[i] = make_uint2(pack2(bflo(a.x) + bflo(b.x), bfhi(a.x) + bfhi(b.x)),
                                pack2(bflo(a.y) + bflo(b.y), bfhi(a.y) + bfhi(b.y)));
}

// ---------------- fc2 [N,128]@[128,10] + log_softmax ----------------
__global__ __launch_bounds__(256) void fc2_kernel(
    const u16* __restrict__ z, const float* __restrict__ W2,
    const float* __restrict__ c2, float* __restrict__ outp, int N) {
  int n = blockIdx.x * 256 + threadIdx.x;
  if (n >= N) return;
  float acc[NCLS];
#pragma unroll
  for (int c = 0; c < NCLS; c++) acc[c] = c2[c];
  const uint2* zr = (const uint2*)(z + (size_t)n * H);
  for (int c4 = 0; c4 < 32; c4++) {
    uint2 u = zr[c4];
    float v[4] = {bflo(u.x), bfhi(u.x), bflo(u.y), bfhi(u.y)};
    int k = c4 * 4;
#pragma unroll
    for (int j = 0; j < 4; j++)
#pragma unroll
      for (int c = 0; c < NCLS; c++) acc[c] += v[j] * W2[(k + j) * NCLS + c];
  }
  float m = acc[0];
#pragma unroll
  for (int c = 1; c < NCLS; c++) m = fmaxf(m, acc[c]);
  float s = 0.f;
#pragma unroll
  for (int c = 0; c < NCLS; c++) s += expf(acc[c] - m);
  float lse = logf(s) + m;
#pragma unroll
  for (int c = 0; c < NCLS; c++) outp[(size_t)n * NCLS + c] = acc[c] - lse;
}

// =============================================================================
extern "C" void kernel_launch(void* const* d_in, const int* in_sizes, int n_in,
                              void* d_out, int out_size, void* d_ws, size_t ws_size,
                              hipStream_t stream) {
  const int N = in_sizes[0] / H;
  const int E = in_sizes[1] / 2;
  const float* x = (const float*)d_in[0];
  const int* ei = (const int*)d_in[1];
  const int* row = ei;
  const int* col = ei + E;
  const int* perm = (const int*)d_in[2];
  const float* W_feat = (const float*)d_in[3];
  const float* b_feat = (const float*)d_in[4];
  const float* W_convs = (const float*)d_in[5];
  const float* b_convs = (const float*)d_in[6];
  const float* W_ea = (const float*)d_in[7];
  const float* b_ea = (const float*)d_in[8];
  const float* W_na = (const float*)d_in[9];
  const float* b_na = (const float*)d_in[10];
  const float* W_ctx = (const float*)d_in[11];
  const float* b_ctx = (const float*)d_in[12];
  const float* W_obj = (const float*)d_in[13];
  const float* b_obj = (const float*)d_in[14];
  const float* W_fc1 = (const float*)d_in[15];
  const float* b_fc1 = (const float*)d_in[16];
  const float* W_fc2 = (const float*)d_in[17];
  const float* b_fc2 = (const float*)d_in[18];
  float* out = (float*)d_out;

  // ---------- workspace carve ----------
  char* base = (char*)d_ws;
  size_t off_b = 0;
  auto alloc = [&](size_t bytes) -> void* {
    void* p = base + off_b;
    off_b = (off_b + bytes + 255) & ~(size_t)255;
    return p;
  };
  size_t NB2 = (size_t)N * H * sizeof(u16);
  u16* bufA = (u16*)alloc(NB2);
  u16* bufB = (u16*)alloc(NB2);
  u16* bufC = (u16*)alloc(NB2);
  u16* bufD = (u16*)alloc(NB2);
  u16* xbf = (u16*)alloc(NB2);
  // zero-region: cnt, deg, degc (one memset)
  int* cnt = (int*)alloc(3 * (size_t)N * 4);
  float* deg = (float*)(cnt + N);
  float* degc = (float*)(cnt + 2 * (size_t)N);
  float* stp = (float*)alloc((size_t)CS_BLOCKS * 256 * 4);  // colstats partials
  int* off = (int*)alloc(((size_t)N + 1) * 4);
  int* cur = (int*)alloc((size_t)N * 4);
  float* dinv = (float*)alloc((size_t)N * 4);
  float* dinvc = (float*)alloc((size_t)N * 4);
  float* dinvo = (float*)alloc((size_t)N * 4);
  float2* na01 = (float2*)alloc((size_t)N * 8);
  float2* p01 = (float2*)alloc((size_t)N * 8);
  float2* q01 = (float2*)alloc((size_t)N * 8);
  int* partial = (int*)alloc(256 * 4);
  int* blockoff = (int*)alloc(256 * 4);
  u16* Wt = (u16*)alloc((size_t)H * H * 2);
  float* cf = (float*)alloc(H * 4);
  float* W2f = (float*)alloc((size_t)H * NCLS * 4);
  float* c2f = (float*)alloc(16 * 4);
  int* csr_src = (int*)alloc((size_t)E * 4);
  int* slot_of = (int*)alloc((size_t)E * 4);
  float* att0s = (float*)alloc((size_t)E * 4);
  float* wn = (float*)alloc((size_t)E * 4);
  float* wa0 = (float*)alloc((size_t)E * 4);
  float* wa1 = (float*)alloc((size_t)E * 4);

  const float invN = 1.0f / (float)N;
  const int gN = (N + 255) / 256;
  const int gE = (E + 255) / 256;
  const int SB = (N + 255) / 256;
  const int gG = (N + 63) / 64;
  const int n4 = N * 32;
  const int gV = (n4 + 255) / 256;
  const int gAgg = (N + 3) / 4;

#define STATS(SRC) colstats_kernel<<<CS_BLOCKS, 256, 0, stream>>>((SRC), N, stp);

  // ---------- one memset for contended accumulators ----------
  hipMemsetAsync(cnt, 0, 3 * (size_t)N * 4, stream);

  // ---------- CSR + degrees ----------
  hist_kernel<<<gE, 256, 0, stream>>>(row, col, E, cnt, deg);
  scanA_kernel<<<SB, 256, 0, stream>>>(cnt, N, partial);
  scanB_kernel<<<1, 256, 0, stream>>>(partial, SB, blockoff);
  scanC_kernel<<<SB, 256, 0, stream>>>(cnt, N, blockoff, off, cur, E);
  place_kernel<<<gE, 256, 0, stream>>>(row, col, E, cur, csr_src, slot_of);
  rsqrt_kernel<<<gN, 256, 0, stream>>>(deg, dinv, N);
  wnorm_kernel<<<gE, 256, 0, stream>>>(csr_src, dinv, wn, E);

  // ---------- feature layer ----------
  xcvt_kernel<<<gV, 256, 0, stream>>>(x, xbf, n4);
  STATS(xbf);
  fold_kernel<<<H, H, 0, stream>>>(stp, CS_BLOCKS, W_feat, b_feat, invN, Wt, cf);
  gemm_kernel<<<gG, 256, 0, stream>>>(xbf, Wt, cf, bufA, N, 1);

  // ---------- 3 GCN convs ----------
  for (int i = 0; i < 3; ++i) {
    STATS(bufA);
    fold_kernel<<<H, H, 0, stream>>>(stp, CS_BLOCKS, W_convs + (size_t)i * H * H,
                                     nullptr, invN, Wt, cf);
    gemm_kernel<<<gG, 256, 0, stream>>>(bufA, Wt, cf, bufC, N, 0);
    agg_kernel<<<gAgg, 256, 0, stream>>>(bufC, csr_src, wn, off, dinv,
                                         b_convs + (size_t)i * H, bufA, N);
  }

  // ---------- attention ----------
  natt_kernel<<<gN, 256, 0, stream>>>(bufA, N, W_na, b_na, W_ea, na01, p01, q01);
  eatt_kernel<<<gE, 256, 0, stream>>>(row, col, E, p01, q01, b_ea, slot_of, att0s, degc);
  rsqrt2_kernel<<<gN, 256, 0, stream>>>(deg, degc, dinvc, dinvo, N);
  wa_kernel<<<gE, 256, 0, stream>>>(csr_src, att0s, dinvc, dinvo, wa0, wa1, E);
  xpre_kernel<<<gV, 256, 0, stream>>>(bufA, na01, bufB, bufC, n4);

  // ---------- ctx conv ----------
  STATS(bufB);
  fold_kernel<<<H, H, 0, stream>>>(stp, CS_BLOCKS, W_ctx, nullptr, invN, Wt, cf);
  gemm_kernel<<<gG, 256, 0, stream>>>(bufB, Wt, cf, bufD, N, 0);
  agg_kernel<<<gAgg, 256, 0, stream>>>(bufD, csr_src, wa0, off, dinvc, b_ctx,
                                       bufB, N);  // xc in B

  // ---------- obj conv ----------
  STATS(bufC);
  fold_kernel<<<H, H, 0, stream>>>(stp, CS_BLOCKS, W_obj, nullptr, invN, Wt, cf);
  gemm_kernel<<<gG, 256, 0, stream>>>(bufC, Wt, cf, bufD, N, 0);
  agg_kernel<<<gAgg, 256, 0, stream>>>(bufD, csr_src, wa1, off, dinvo, b_obj,
                                       bufA, N);  // xo in A

  // ---------- h_co = xc[perm] + xo ----------
  permadd_kernel<<<gV, 256, 0, stream>>>(bufB, bufA, perm, bufD, n4);

  // ---------- 3 readouts ----------
  const u16* Xin[3] = {bufB, bufA, bufD};
  for (int j = 0; j < 3; ++j) {
    STATS(Xin[j]);
    fold_kernel<<<H, H, 0, stream>>>(stp, CS_BLOCKS, W_fc1 + (size_t)j * H * H,
                                     b_fc1 + (size_t)j * H, invN, Wt, cf);
    gemm_kernel<<<gG, 256, 0, stream>>>(Xin[j], Wt, cf, bufC, N, 1);
    STATS(bufC);
    fold10_kernel<<<NCLS, H, 0, stream>>>(stp, CS_BLOCKS, W_fc2 + (size_t)j * H * NCLS,
                                          b_fc2 + (size_t)j * NCLS, invN, W2f, c2f);
    fc2_kernel<<<gN, 256, 0, stream>>>(bufC, W2f, c2f, out + (size_t)j * N * NCLS, N);
  }
#undef STATS
}

// Round 7
// 1293.537 us; speedup vs baseline: 1.9503x; 1.1852x over previous
//
#include <hip/hip_runtime.h>
#include <math.h>

#define H 128
#define NCLS 10
#define EPS 1e-5f
#define BN_BETA 1e-4f
#define CS_BLOCKS 256

typedef unsigned short u16;
typedef unsigned int u32;
typedef __attribute__((ext_vector_type(8))) short short8;
typedef __attribute__((ext_vector_type(4))) float floatx4;

// ---- bf16 helpers (bit ops; RNE) ----
__device__ inline float bflo(u32 u) { union { u32 i; float f; } a; a.i = u << 16; return a.f; }
__device__ inline float bfhi(u32 u) { union { u32 i; float f; } a; a.i = u & 0xffff0000u; return a.f; }
__device__ inline u16 f2bf(float f) {
  union { float f; u32 i; } v; v.f = f;
  return (u16)((v.i + 0x7fff + ((v.i >> 16) & 1)) >> 16);
}
__device__ inline u32 pack2(float a, float b) { return (u32)f2bf(a) | ((u32)f2bf(b) << 16); }

// ================= x fp32 -> bf16, fused column stats (no atomics) ==========
__global__ __launch_bounds__(256) void xcvt_stats_kernel(
    const float* __restrict__ x, u16* __restrict__ xb, int n4, float* __restrict__ stp) {
  int tid = threadIdx.x;
  int lane = tid & 63, wave = tid >> 6;
  float s[4] = {0, 0, 0, 0}, q[4] = {0, 0, 0, 0};
  int step = gridDim.x * 256;  // multiple of 32 -> (i&31) invariant per thread
  for (int i = blockIdx.x * 256 + tid; i < n4; i += step) {
    float4 v = ((const float4*)x)[i];
    ((uint2*)xb)[i] = make_uint2(pack2(v.x, v.y), pack2(v.z, v.w));
    s[0] += v.x; q[0] += v.x * v.x; s[1] += v.y; q[1] += v.y * v.y;
    s[2] += v.z; q[2] += v.z * v.z; s[3] += v.w; q[3] += v.w * v.w;
  }
#pragma unroll
  for (int k = 0; k < 4; k++) { s[k] += __shfl_xor(s[k], 32); q[k] += __shfl_xor(q[k], 32); }
  __shared__ float sm[4][256];
  int col = (lane & 31) * 4;
  if (lane < 32) {
#pragma unroll
    for (int k = 0; k < 4; k++) { sm[wave][col + k] = s[k]; sm[wave][128 + col + k] = q[k]; }
  }
  __syncthreads();
  stp[(size_t)blockIdx.x * 256 + tid] = sm[0][tid] + sm[1][tid] + sm[2][tid] + sm[3][tid];
}

// ================= column stats over bf16 [N,128] (no atomics) ===============
__device__ inline void colstats_body(const u16* __restrict__ X, int N, int b,
                                     float* __restrict__ outrow) {
  int tid = threadIdx.x;
  int li = tid & 15, rg = tid >> 4;
  int wave = tid >> 6, lane = tid & 63;
  const uint4* T = (const uint4*)X;
  float s[8] = {0, 0, 0, 0, 0, 0, 0, 0}, q[8] = {0, 0, 0, 0, 0, 0, 0, 0};
  for (int r = b * 16 + rg; r < N; r += CS_BLOCKS * 16) {
    uint4 u = T[(size_t)r * 16 + li];
    float f[8] = {bflo(u.x), bfhi(u.x), bflo(u.y), bfhi(u.y),
                  bflo(u.z), bfhi(u.z), bflo(u.w), bfhi(u.w)};
#pragma unroll
    for (int j = 0; j < 8; j++) { s[j] += f[j]; q[j] += f[j] * f[j]; }
  }
#pragma unroll
  for (int j = 0; j < 8; j++) {
    s[j] += __shfl_xor(s[j], 16); s[j] += __shfl_xor(s[j], 32);
    q[j] += __shfl_xor(q[j], 16); q[j] += __shfl_xor(q[j], 32);
  }
  __shared__ float sm[4][256];
  if ((lane & 48) == 0) {
#pragma unroll
    for (int j = 0; j < 8; j++) {
      sm[wave][li * 8 + j] = s[j];
      sm[wave][128 + li * 8 + j] = q[j];
    }
  }
  __syncthreads();
  outrow[tid] = sm[0][tid] + sm[1][tid] + sm[2][tid] + sm[3][tid];
}

__global__ __launch_bounds__(256) void colstats_kernel(
    const u16* __restrict__ X, int N, float* __restrict__ stp) {
  colstats_body(X, N, blockIdx.x, stp + (size_t)blockIdx.x * 256);
}

// batched over up to 3 tensors; launch grid = k*CS_BLOCKS
__global__ __launch_bounds__(256) void colstats3_kernel(
    const u16* __restrict__ z0, const u16* __restrict__ z1, const u16* __restrict__ z2,
    int N, float* __restrict__ stpZ) {
  int j = blockIdx.x >> 8, b = blockIdx.x & 255;
  const u16* X = (j == 0) ? z0 : (j == 1) ? z1 : z2;
  colstats_body(X, N, b, stpZ + (size_t)j * 65536 + (size_t)b * 256);
}

// ================= fold: reduce partials + BN-fold into Wt (bf16,T) ==========
__device__ inline void fold_body(const float* __restrict__ P, int nb, int stride, int off0,
                                 const float* __restrict__ W, const float* __restrict__ bias,
                                 float invN, int k, u16* __restrict__ Wt, float* __restrict__ cf) {
  int f = threadIdx.x;
  float su = 0.f, sq = 0.f;
  for (int b = 0; b < nb; b++) {
    su += P[(size_t)b * stride + off0 + f];
    sq += P[(size_t)b * stride + off0 + 128 + f];
  }
  float mu = su * invN;
  float var = sq * invN - mu * mu;
  float s = 1.0f / sqrtf(fmaxf(var, 0.f) + EPS);
  float w = W[(size_t)f * H + k];
  Wt[(size_t)k * H + f] = f2bf(s * w);
  __shared__ float red[H];
  red[f] = (BN_BETA - mu * s) * w;
  __syncthreads();
  for (int o = 64; o > 0; o >>= 1) {
    if (f < o) red[f] += red[f + o];
    __syncthreads();
  }
  if (f == 0) cf[k] = red[0] + (bias ? bias[k] : 0.f);
}

__global__ __launch_bounds__(128) void fold_kernel(
    const float* __restrict__ P, int nb, const float* __restrict__ W,
    const float* __restrict__ bias, float invN, u16* __restrict__ Wt, float* __restrict__ cf) {
  fold_body(P, nb, 256, 0, W, bias, invN, blockIdx.x, Wt, cf);
}

// ctx+obj batched: stats from xpre partials (row=512: [c_s|c_q|o_s|o_q])
__global__ __launch_bounds__(128) void fold2_kernel(
    const float* __restrict__ P, int nb, const float* __restrict__ W0,
    const float* __restrict__ W1, float invN, u16* __restrict__ Wt2, float* __restrict__ cf2) {
  int j = blockIdx.x >> 7, k = blockIdx.x & 127;
  fold_body(P, nb, 512, j * 256, j ? W1 : W0, nullptr, invN, k, Wt2 + (size_t)j * H * H,
            cf2 + j * H);
}

// fc1 x3 batched
__global__ __launch_bounds__(128) void fold3_kernel(
    const float* __restrict__ PC, const float* __restrict__ PO, const float* __restrict__ PCO,
    int nb, const float* __restrict__ W_fc1, const float* __restrict__ b_fc1, float invN,
    u16* __restrict__ Wt3, float* __restrict__ cf3) {
  int j = blockIdx.x >> 7, k = blockIdx.x & 127;
  const float* P = (j == 0) ? PC : (j == 1) ? PO : PCO;
  fold_body(P, nb, 256, 0, W_fc1 + (size_t)j * H * H, b_fc1 + j * H, invN, k,
            Wt3 + (size_t)j * H * H, cf3 + j * H);
}

// fc2 batched (Kout=10, fp32 out); j relative to passed base pointers
__global__ __launch_bounds__(128) void fold10x3_kernel(
    const float* __restrict__ stpZ, int nb, const float* __restrict__ W_fc2,
    const float* __restrict__ b_fc2, float invN, float* __restrict__ W2f,
    float* __restrict__ c2f) {
  int j = blockIdx.x / NCLS, k = blockIdx.x % NCLS;
  const float* P = stpZ + (size_t)j * 65536;
  int f = threadIdx.x;
  float su = 0.f, sq = 0.f;
  for (int b = 0; b < nb; b++) {
    su += P[(size_t)b * 256 + f];
    sq += P[(size_t)b * 256 + 128 + f];
  }
  float mu = su * invN;
  float var = sq * invN - mu * mu;
  float s = 1.0f / sqrtf(fmaxf(var, 0.f) + EPS);
  float w = W_fc2[(size_t)j * H * NCLS + (size_t)f * NCLS + k];
  W2f[(size_t)j * H * NCLS + (size_t)f * NCLS + k] = s * w;
  __shared__ float red[H];
  red[f] = (BN_BETA - mu * s) * w;
  __syncthreads();
  for (int o = 64; o > 0; o >>= 1) {
    if (f < o) red[f] += red[f + o];
    __syncthreads();
  }
  if (f == 0) c2f[j * 16 + k] = red[0] + b_fc2[j * NCLS + k];
}

// ================= bf16 MFMA GEMM =================
__device__ inline void gemm_body(const u16* __restrict__ A, const u16* __restrict__ Bt,
                                 const float* __restrict__ bias, u16* __restrict__ C, int N,
                                 int relu, int blk) {
  int tid = threadIdx.x;
  int wave = tid >> 6, lane = tid & 63;
  int l15 = lane & 15, quad = lane >> 4;
  int row0 = (blk * 4 + wave) * 16;
  if (row0 >= N) return;
  int arow = row0 + l15;
  short8 a[4];
  short8 z8 = {0, 0, 0, 0, 0, 0, 0, 0};
#pragma unroll
  for (int k4 = 0; k4 < 4; k4++)
    a[k4] = (arow < N) ? *(const short8*)(A + (size_t)arow * H + k4 * 32 + quad * 8) : z8;
#pragma unroll
  for (int nt = 0; nt < 8; nt++) {
    floatx4 acc = {0.f, 0.f, 0.f, 0.f};
    const u16* bp = Bt + (size_t)(nt * 16 + l15) * H + quad * 8;
#pragma unroll
    for (int k4 = 0; k4 < 4; k4++) {
      short8 b = *(const short8*)(bp + k4 * 32);
      acc = __builtin_amdgcn_mfma_f32_16x16x32_bf16(a[k4], b, acc, 0, 0, 0);
    }
    int col = nt * 16 + l15;
    float bs = bias[col];
#pragma unroll
    for (int r = 0; r < 4; r++) {
      int row = row0 + quad * 4 + r;
      if (row < N) {
        float v = acc[r] + bs;
        if (relu) v = fmaxf(v, 0.f);
        C[(size_t)row * H + col] = f2bf(v);
      }
    }
  }
}

__global__ __launch_bounds__(256) void gemm_kernel(
    const u16* __restrict__ A, const u16* __restrict__ Bt, const float* __restrict__ bias,
    u16* __restrict__ C, int N, int relu) {
  gemm_body(A, Bt, bias, C, N, relu, blockIdx.x);
}

__global__ __launch_bounds__(256) void gemm2_kernel(
    const u16* __restrict__ A0, const u16* __restrict__ A1, const u16* __restrict__ Wt2,
    const float* __restrict__ cf2, u16* __restrict__ C0, u16* __restrict__ C1, int N,
    int gG, int relu) {
  int j = blockIdx.x / gG, blk = blockIdx.x % gG;
  gemm_body(j ? A1 : A0, Wt2 + (size_t)j * H * H, cf2 + j * H, j ? C1 : C0, N, relu, blk);
}

// ================= CSR build =================
__global__ __launch_bounds__(256) void hist_kernel(
    const int* __restrict__ row, const int* __restrict__ col, int E,
    int* __restrict__ cnt, float* __restrict__ deg) {
  int e = blockIdx.x * 256 + threadIdx.x;
  if (e < E) {
    atomicAdd(&cnt[col[e]], 1);
    atomicAdd(&deg[row[e]], 1.0f);
  }
}

__global__ __launch_bounds__(256) void scanA_rsqrt_kernel(
    const int* __restrict__ cnt, const float* __restrict__ deg, int N,
    int* __restrict__ partial, float* __restrict__ dinv) {
  int i = blockIdx.x * 256 + threadIdx.x;
  if (i < N) dinv[i] = 1.0f / sqrtf(deg[i] + 1.0f);
  __shared__ int sd[256];
  sd[threadIdx.x] = (i < N) ? cnt[i] : 0;
  __syncthreads();
  for (int o = 128; o > 0; o >>= 1) {
    if (threadIdx.x < o) sd[threadIdx.x] += sd[threadIdx.x + o];
    __syncthreads();
  }
  if (threadIdx.x == 0) partial[blockIdx.x] = sd[0];
}

__global__ __launch_bounds__(256) void scanB_kernel(const int* __restrict__ partial, int nb,
                                                    int* __restrict__ blockoff) {
  __shared__ int sd[256];
  int t = threadIdx.x;
  int v = (t < nb) ? partial[t] : 0;
  sd[t] = v;
  __syncthreads();
  for (int o = 1; o < 256; o <<= 1) {
    int x = (t >= o) ? sd[t - o] : 0;
    __syncthreads();
    sd[t] += x;
    __syncthreads();
  }
  blockoff[t] = sd[t] - v;
}

__global__ __launch_bounds__(256) void scanC_kernel(
    const int* __restrict__ cnt, int N, const int* __restrict__ blockoff,
    int* __restrict__ off, int* __restrict__ cur, int E) {
  __shared__ int sd[256];
  int t = threadIdx.x;
  int i = blockIdx.x * 256 + t;
  int v = (i < N) ? cnt[i] : 0;
  sd[t] = v;
  __syncthreads();
  for (int o = 1; o < 256; o <<= 1) {
    int x = (t >= o) ? sd[t - o] : 0;
    __syncthreads();
    sd[t] += x;
    __syncthreads();
  }
  if (i < N) {
    int ex = blockoff[blockIdx.x] + sd[t] - v;
    off[i] = ex;
    cur[i] = ex;
  }
  if (i == 0) off[N] = E;
}

// place + wn (dinv[src]) fused
__global__ __launch_bounds__(256) void place_kernel(
    const int* __restrict__ row, const int* __restrict__ col, int E,
    int* __restrict__ cur, const float* __restrict__ dinv,
    int* __restrict__ csr_src, int* __restrict__ slot_of, float* __restrict__ wn) {
  int e = blockIdx.x * 256 + threadIdx.x;
  if (e < E) {
    int r = row[e];
    int slot = atomicAdd(&cur[col[e]], 1);
    csr_src[slot] = r;
    slot_of[e] = slot;
    wn[slot] = dinv[r];
  }
}

__global__ __launch_bounds__(256) void rsqrt2_kernel(
    const float* __restrict__ deg, const float* __restrict__ degc,
    float* __restrict__ dinvc, float* __restrict__ dinvo, int N) {
  int v = blockIdx.x * 256 + threadIdx.x;
  if (v < N) {
    float dc = degc[v];
    dinvc[v] = 1.0f / sqrtf(dc + 1.0f);
    dinvo[v] = 1.0f / sqrtf(deg[v] - dc + 1.0f);
  }
}

// wa0/wa1 may alias slot_of/wn (those are dead by now; only csr_src/att0s read)
__global__ __launch_bounds__(256) void wa_kernel(
    const int* __restrict__ csr_src, const float* __restrict__ att0s,
    const float* __restrict__ dinvc, const float* __restrict__ dinvo,
    float* __restrict__ wa0, float* __restrict__ wa1, int E) {
  int i = blockIdx.x * 256 + threadIdx.x;
  if (i < E) {
    int s = csr_src[i];
    float a0 = att0s[i];
    wa0[i] = a0 * dinvc[s];
    wa1[i] = (1.0f - a0) * dinvo[s];
  }
}

// ================= aggregation: 4 groups x 16 lanes, unroll 8 ================
#define ACC8(A, U, W)                                             \
  A[0] += (W) * bflo(U.x); A[1] += (W) * bfhi(U.x);               \
  A[2] += (W) * bflo(U.y); A[3] += (W) * bfhi(U.y);               \
  A[4] += (W) * bflo(U.z); A[5] += (W) * bfhi(U.z);               \
  A[6] += (W) * bflo(U.w); A[7] += (W) * bfhi(U.w);

__global__ __launch_bounds__(256) void agg_kernel(
    const u16* __restrict__ t, const int* __restrict__ csr_src,
    const float* __restrict__ wseg, const int* __restrict__ off,
    const float* __restrict__ dinv, const float* __restrict__ bias,
    u16* __restrict__ out, int N) {
  int v = blockIdx.x * 4 + (threadIdx.x >> 6);
  if (v >= N) return;
  int lane = threadIdx.x & 63;
  int g = lane >> 4, li = lane & 15;
  const uint4* T = (const uint4*)t;
  float dv = dinv[v];
  float acc[8] = {0.f, 0.f, 0.f, 0.f, 0.f, 0.f, 0.f, 0.f};
  if (g == 0) {
    uint4 u = T[(size_t)v * 16 + li];
    float w0 = dv * dv;
    ACC8(acc, u, w0)
  }
  int s0 = off[v], s1 = off[v + 1];
  for (int s = s0; s < s1; s += 32) {
    int ix[8]; float wv[8];
#pragma unroll
    for (int u = 0; u < 8; u++) {
      int e = s + g + u * 4;
      bool ok = e < s1;
      int e2 = ok ? e : s0;
      ix[u] = csr_src[e2];
      wv[u] = ok ? wseg[e2] : 0.f;
    }
    uint4 uu[8];
#pragma unroll
    for (int u = 0; u < 8; u++) uu[u] = T[(size_t)ix[u] * 16 + li];
#pragma unroll
    for (int u = 0; u < 8; u++) { float w = wv[u] * dv; ACC8(acc, uu[u], w) }
  }
#pragma unroll
  for (int j = 0; j < 8; j++) {
    acc[j] += __shfl_xor(acc[j], 16);
    acc[j] += __shfl_xor(acc[j], 32);
  }
  if (g == 0) {
    float o[8];
#pragma unroll
    for (int j = 0; j < 8; j++) o[j] = fmaxf(acc[j] + bias[li * 8 + j], 0.f);
    uint4 w4;
    w4.x = pack2(o[0], o[1]); w4.y = pack2(o[2], o[3]);
    w4.z = pack2(o[4], o[5]); w4.w = pack2(o[6], o[7]);
    ((uint4*)out)[(size_t)v * 16 + li] = w4;
  }
}

// ---- dual-table aggregation (ctx + obj share the gather pattern) ----
__global__ __launch_bounds__(256) void aggdual_kernel(
    const u16* __restrict__ tc, const u16* __restrict__ to_, const int* __restrict__ csr_src,
    const float* __restrict__ wa0, const float* __restrict__ wa1, const int* __restrict__ off,
    const float* __restrict__ dinvc, const float* __restrict__ dinvo,
    const float* __restrict__ bc, const float* __restrict__ bo,
    u16* __restrict__ outc, u16* __restrict__ outo, int N) {
  int v = blockIdx.x * 4 + (threadIdx.x >> 6);
  if (v >= N) return;
  int lane = threadIdx.x & 63;
  int g = lane >> 4, li = lane & 15;
  const uint4* TC = (const uint4*)tc;
  const uint4* TO = (const uint4*)to_;
  float dvc = dinvc[v], dvo = dinvo[v];
  float ac[8] = {0.f, 0.f, 0.f, 0.f, 0.f, 0.f, 0.f, 0.f};
  float ao[8] = {0.f, 0.f, 0.f, 0.f, 0.f, 0.f, 0.f, 0.f};
  if (g == 0) {
    uint4 uc = TC[(size_t)v * 16 + li];
    uint4 uo = TO[(size_t)v * 16 + li];
    float wc = dvc * dvc, wo = dvo * dvo;
    ACC8(ac, uc, wc)
    ACC8(ao, uo, wo)
  }
  int s0 = off[v], s1 = off[v + 1];
  for (int s = s0; s < s1; s += 16) {
    int ix[4]; float w0[4], w1[4];
#pragma unroll
    for (int u = 0; u < 4; u++) {
      int e = s + g + u * 4;
      bool ok = e < s1;
      int e2 = ok ? e : s0;
      ix[u] = csr_src[e2];
      w0[u] = ok ? wa0[e2] : 0.f;
      w1[u] = ok ? wa1[e2] : 0.f;
    }
    uint4 uc[4], uo[4];
#pragma unroll
    for (int u = 0; u < 4; u++) {
      uc[u] = TC[(size_t)ix[u] * 16 + li];
      uo[u] = TO[(size_t)ix[u] * 16 + li];
    }
#pragma unroll
    for (int u = 0; u < 4; u++) {
      float wc = w0[u] * dvc; ACC8(ac, uc[u], wc)
      float wo = w1[u] * dvo; ACC8(ao, uo[u], wo)
    }
  }
#pragma unroll
  for (int j = 0; j < 8; j++) {
    ac[j] += __shfl_xor(ac[j], 16); ac[j] += __shfl_xor(ac[j], 32);
    ao[j] += __shfl_xor(ao[j], 16); ao[j] += __shfl_xor(ao[j], 32);
  }
  if (g == 0) {
    float oc[8], oo[8];
#pragma unroll
    for (int j = 0; j < 8; j++) {
      oc[j] = fmaxf(ac[j] + bc[li * 8 + j], 0.f);
      oo[j] = fmaxf(ao[j] + bo[li * 8 + j], 0.f);
    }
    uint4 wc4, wo4;
    wc4.x = pack2(oc[0], oc[1]); wc4.y = pack2(oc[2], oc[3]);
    wc4.z = pack2(oc[4], oc[5]); wc4.w = pack2(oc[6], oc[7]);
    wo4.x = pack2(oo[0], oo[1]); wo4.y = pack2(oo[2], oo[3]);
    wo4.z = pack2(oo[4], oo[5]); wo4.w = pack2(oo[6], oo[7]);
    ((uint4*)outc)[(size_t)v * 16 + li] = wc4;
    ((uint4*)outo)[(size_t)v * 16 + li] = wo4;
  }
}

// ================= node attention + edge-att p,q factors =====================
__global__ __launch_bounds__(256) void natt_kernel(
    const u16* __restrict__ h, int N,
    const float* __restrict__ W_na, const float* __restrict__ b_na,
    const float* __restrict__ W_ea,
    float2* __restrict__ na01, float2* __restrict__ p01, float2* __restrict__ q01) {
  int n = blockIdx.x * 256 + threadIdx.x;
  if (n >= N) return;
  float sa0 = 0, sa1 = 0, sp0 = 0, sp1 = 0, sq0 = 0, sq1 = 0;
  const uint2* hr = (const uint2*)(h + (size_t)n * H);
  for (int c = 0; c < 32; c++) {
    uint2 u = hr[c];
    float v0 = bflo(u.x), v1 = bfhi(u.x), v2 = bflo(u.y), v3 = bfhi(u.y);
    int k = c * 4;
    sa0 += v0 * W_na[k * 2] + v1 * W_na[k * 2 + 2] + v2 * W_na[k * 2 + 4] + v3 * W_na[k * 2 + 6];
    sa1 += v0 * W_na[k * 2 + 1] + v1 * W_na[k * 2 + 3] + v2 * W_na[k * 2 + 5] + v3 * W_na[k * 2 + 7];
    sp0 += v0 * W_ea[k * 2] + v1 * W_ea[k * 2 + 2] + v2 * W_ea[k * 2 + 4] + v3 * W_ea[k * 2 + 6];
    sp1 += v0 * W_ea[k * 2 + 1] + v1 * W_ea[k * 2 + 3] + v2 * W_ea[k * 2 + 5] + v3 * W_ea[k * 2 + 7];
    sq0 += v0 * W_ea[(H + k) * 2] + v1 * W_ea[(H + k) * 2 + 2] + v2 * W_ea[(H + k) * 2 + 4] + v3 * W_ea[(H + k) * 2 + 6];
    sq1 += v0 * W_ea[(H + k) * 2 + 1] + v1 * W_ea[(H + k) * 2 + 3] + v2 * W_ea[(H + k) * 2 + 5] + v3 * W_ea[(H + k) * 2 + 7];
  }
  sa0 += b_na[0]; sa1 += b_na[1];
  float m = fmaxf(sa0, sa1);
  float e0 = expf(sa0 - m), e1 = expf(sa1 - m);
  float inv = 1.f / (e0 + e1);
  na01[n] = make_float2(e0 * inv, e1 * inv);
  p01[n] = make_float2(sp0, sp1);
  q01[n] = make_float2(sq0, sq1);
}

// ================= xpre with fused dual stats (row=512) ======================
__global__ __launch_bounds__(256) void xpre_stats_kernel(
    const u16* __restrict__ h, const float2* __restrict__ na01,
    u16* __restrict__ xc, u16* __restrict__ xo, int n4, float* __restrict__ stp) {
  int tid = threadIdx.x;
  int lane = tid & 63, wave = tid >> 6;
  float sc[4] = {0, 0, 0, 0}, qc[4] = {0, 0, 0, 0};
  float so[4] = {0, 0, 0, 0}, qo[4] = {0, 0, 0, 0};
  int step = gridDim.x * 256;
  for (int i = blockIdx.x * 256 + tid; i < n4; i += step) {
    int n = i >> 5;
    uint2 u = ((const uint2*)h)[i];
    float v0 = bflo(u.x), v1 = bfhi(u.x), v2 = bflo(u.y), v3 = bfhi(u.y);
    float2 ab = na01[n];
    float a = ab.x, b = ab.y;
    float c0 = v0 * a, c1 = v1 * a, c2 = v2 * a, c3 = v3 * a;
    float o0 = v0 * b, o1 = v1 * b, o2 = v2 * b, o3 = v3 * b;
    ((uint2*)xc)[i] = make_uint2(pack2(c0, c1), pack2(c2, c3));
    ((uint2*)xo)[i] = make_uint2(pack2(o0, o1), pack2(o2, o3));
    sc[0] += c0; qc[0] += c0 * c0; sc[1] += c1; qc[1] += c1 * c1;
    sc[2] += c2; qc[2] += c2 * c2; sc[3] += c3; qc[3] += c3 * c3;
    so[0] += o0; qo[0] += o0 * o0; so[1] += o1; qo[1] += o1 * o1;
    so[2] += o2; qo[2] += o2 * o2; so[3] += o3; qo[3] += o3 * o3;
  }
#pragma unroll
  for (int k = 0; k < 4; k++) {
    sc[k] += __shfl_xor(sc[k], 32); qc[k] += __shfl_xor(qc[k], 32);
    so[k] += __shfl_xor(so[k], 32); qo[k] += __shfl_xor(qo[k], 32);
  }
  __shared__ float sm[4][512];
  int col = (lane & 31) * 4;
  if (lane < 32) {
#pragma unroll
    for (int k = 0; k < 4; k++) {
      sm[wave][col + k] = sc[k];
      sm[wave][128 + col + k] = qc[k];
      sm[wave][256 + col + k] = so[k];
      sm[wave][384 + col + k] = qo[k];
    }
  }
  __syncthreads();
  float r0 = sm[0][tid] + sm[1][tid] + sm[2][tid] + sm[3][tid];
  float r1 = sm[0][256 + tid] + sm[1][256 + tid] + sm[2][256 + tid] + sm[3][256 + tid];
  stp[(size_t)blockIdx.x * 512 + tid] = r0;
  stp[(size_t)blockIdx.x * 512 + 256 + tid] = r1;
}

// ================= edge attention -> CSR-order att0 + degc ===================
__global__ __launch_bounds__(256) void eatt_kernel(
    const int* __restrict__ row, const int* __restrict__ col, int E,
    const float2* __restrict__ p01, const float2* __restrict__ q01,
    const float* __restrict__ b_ea, const int* __restrict__ slot_of,
    float* __restrict__ att0s, float* __restrict__ degc) {
  int e = blockIdx.x * 256 + threadIdx.x;
  if (e >= E) return;
  int r = row[e], c = col[e];
  float2 p = p01[r], q = q01[c];
  float l0 = p.x + q.x + b_ea[0];
  float l1 = p.y + q.y + b_ea[1];
  float a0 = 1.0f / (1.0f + expf(l1 - l0));
  att0s[slot_of[e]] = a0;
  atomicAdd(&degc[r], a0);
}

// ================= h_co = xc[perm] + xo, fused stats =========================
__global__ __launch_bounds__(256) void permadd_stats_kernel(
    const u16* __restrict__ xc, const u16* __restrict__ xo,
    const int* __restrict__ perm, u16* __restrict__ out, int n4, float* __restrict__ stp) {
  int tid = threadIdx.x;
  int lane = tid & 63, wave = tid >> 6;
  float s[4] = {0, 0, 0, 0}, q[4] = {0, 0, 0, 0};
  int step = gridDim.x * 256;
  for (int i = blockIdx.x * 256 + tid; i < n4; i += step) {
    int n = i >> 5, k = i & 31;
    int p = perm[n];
    uint2 a = ((const uint2*)xc)[(size_t)p * 32 + k];
    uint2 b = ((const uint2*)xo)[i];
    float f0 = bflo(a.x) + bflo(b.x), f1 = bfhi(a.x) + bfhi(b.x);
    float f2 = bflo(a.y) + bflo(b.y), f3 = bfhi(a.y) + bfhi(b.y);
    ((uint2*)out)[i] = make_uint2(pack2(f0, f1), pack2(f2, f3));
    s[0] += f0; q[0] += f0 * f0; s[1] += f1; q[1] += f1 * f1;
    s[2] += f2; q[2] += f2 * f2; s[3] += f3; q[3] += f3 * f3;
  }
#pragma unroll
  for (int k = 0; k < 4; k++) { s[k] += __shfl_xor(s[k], 32); q[k] += __shfl_xor(q[k], 32); }
  __shared__ float sm[4][256];
  int col = (lane & 31) * 4;
  if (lane < 32) {
#pragma unroll
    for (int k = 0; k < 4; k++) { sm[wave][col + k] = s[k]; sm[wave][128 + col + k] = q[k]; }
  }
  __syncthreads();
  stp[(size_t)blockIdx.x * 256 + tid] = sm[0][tid] + sm[1][tid] + sm[2][tid] + sm[3][tid];
}

// ================= fc2 batched: [N,128]@[128,10] + log_softmax ===============
// j relative to passed base pointers; launch grid = k*gN
__global__ __launch_bounds__(256) void fc2x3_kernel(
    const u16* __restrict__ z0, const u16* __restrict__ z1, const u16* __restrict__ z2,
    const float* __restrict__ W2f, const float* __restrict__ c2f,
    float* __restrict__ outp, int N, int gN) {
  int j = blockIdx.x / gN, blk = blockIdx.x % gN;
  int n = blk * 256 + threadIdx.x;
  if (n >= N) return;
  const u16* z = (j == 0) ? z0 : (j == 1) ? z1 : z2;
  const float* W2 = W2f + (size_t)j * H * NCLS;
  const float* c2 = c2f + j * 16;
  float* op = outp + (size_t)j * N * NCLS;
  float acc[NCLS];
#pragma unroll
  for (int c = 0; c < NCLS; c++) acc[c] = c2[c];
  const uint2* zr = (const uint2*)(z + (size_t)n * H);
  for (int c4 = 0; c4 < 32; c4++) {
    uint2 u = zr[c4];
    float v[4] = {bflo(u.x), bfhi(u.x), bflo(u.y), bfhi(u.y)};
    int k = c4 * 4;
#pragma unroll
    for (int jj = 0; jj < 4; jj++)
#pragma unroll
      for (int c = 0; c < NCLS; c++) acc[c] += v[jj] * W2[(k + jj) * NCLS + c];
  }
  float m = acc[0];
#pragma unroll
  for (int c = 1; c < NCLS; c++) m = fmaxf(m, acc[c]);
  float s = 0.f;
#pragma unroll
  for (int c = 0; c < NCLS; c++) s += expf(acc[c] - m);
  float lse = logf(s) + m;
#pragma unroll
  for (int c = 0; c < NCLS; c++) op[(size_t)n * NCLS + c] = acc[c] - lse;
}

// =============================================================================
extern "C" void kernel_launch(void* const* d_in, const int* in_sizes, int n_in,
                              void* d_out, int out_size, void* d_ws, size_t ws_size,
                              hipStream_t stream) {
  const int N = in_sizes[0] / H;
  const int E = in_sizes[1] / 2;
  const float* x = (const float*)d_in[0];
  const int* ei = (const int*)d_in[1];
  const int* row = ei;
  const int* col = ei + E;
  const int* perm = (const int*)d_in[2];
  const float* W_feat = (const float*)d_in[3];
  const float* b_feat = (const float*)d_in[4];
  const float* W_convs = (const float*)d_in[5];
  const float* b_convs = (const float*)d_in[6];
  const float* W_ea = (const float*)d_in[7];
  const float* b_ea = (const float*)d_in[8];
  const float* W_na = (const float*)d_in[9];
  const float* b_na = (const float*)d_in[10];
  const float* W_ctx = (const float*)d_in[11];
  const float* b_ctx = (const float*)d_in[12];
  const float* W_obj = (const float*)d_in[13];
  const float* b_obj = (const float*)d_in[14];
  const float* W_fc1 = (const float*)d_in[15];
  const float* b_fc1 = (const float*)d_in[16];
  const float* W_fc2 = (const float*)d_in[17];
  const float* b_fc2 = (const float*)d_in[18];
  float* out = (float*)d_out;

  // ---------- workspace carve (total ~82 MB; r5's 86 MB was proven safe) ----
  char* base = (char*)d_ws;
  size_t off_b = 0;
  auto alloc = [&](size_t bytes) -> void* {
    void* p = base + off_b;
    off_b = (off_b + bytes + 255) & ~(size_t)255;
    return p;
  };
  size_t NB2 = (size_t)N * H * sizeof(u16);
  u16* bufA = (u16*)alloc(NB2);  // h chain; t_obj; z0; z2
  u16* bufB = (u16*)alloc(NB2);  // xc_pre -> xc
  u16* bufC = (u16*)alloc(NB2);  // conv temp t; xo_pre -> xo
  u16* bufD = (u16*)alloc(NB2);  // t_ctx; h_co
  u16* xbf = (u16*)alloc(NB2);   // x bf16; z1
  int* cnt = (int*)alloc(3 * (size_t)N * 4);  // cnt, deg, degc (one memset)
  float* deg = (float*)(cnt + N);
  float* degc = (float*)(cnt + 2 * (size_t)N);
  float* stpX = (float*)alloc((size_t)CS_BLOCKS * 256 * 4);
  float* stpPre = (float*)alloc((size_t)CS_BLOCKS * 512 * 4);
  float* stpC = (float*)alloc((size_t)CS_BLOCKS * 256 * 4);
  float* stpO = (float*)alloc((size_t)CS_BLOCKS * 256 * 4);
  float* stpCO = (float*)alloc((size_t)CS_BLOCKS * 256 * 4);
  float* stpZ = (float*)alloc(3 * (size_t)CS_BLOCKS * 256 * 4);
  int* off = (int*)alloc(((size_t)N + 1) * 4);
  int* cur = (int*)alloc((size_t)N * 4);
  float* dinv = (float*)alloc((size_t)N * 4);
  float* dinvc = (float*)alloc((size_t)N * 4);
  float* dinvo = (float*)alloc((size_t)N * 4);
  float2* na01 = (float2*)alloc((size_t)N * 8);
  float2* p01 = (float2*)alloc((size_t)N * 8);
  float2* q01 = (float2*)alloc((size_t)N * 8);
  int* partial = (int*)alloc(256 * 4);
  int* blockoff = (int*)alloc(256 * 4);
  u16* Wt = (u16*)alloc((size_t)H * H * 2);
  u16* Wt2 = (u16*)alloc(2 * (size_t)H * H * 2);
  u16* Wt3 = (u16*)alloc(3 * (size_t)H * H * 2);
  float* cf = (float*)alloc(H * 4);
  float* cf2 = (float*)alloc(2 * H * 4);
  float* cf3 = (float*)alloc(3 * H * 4);
  float* W2f = (float*)alloc(3 * (size_t)H * NCLS * 4);
  float* c2f = (float*)alloc(3 * 16 * 4);
  int* csr_src = (int*)alloc((size_t)E * 4);
  int* slot_of = (int*)alloc((size_t)E * 4);   // dead after eatt -> reused as wa0
  float* att0s = (float*)alloc((size_t)E * 4);
  float* wn = (float*)alloc((size_t)E * 4);    // dead after conv aggs -> reused as wa1
  float* wa0 = (float*)slot_of;  // ALIAS (disjoint lifetime)
  float* wa1 = wn;               // ALIAS (disjoint lifetime)

  const float invN = 1.0f / (float)N;
  const int gN = (N + 255) / 256;
  const int gE = (E + 255) / 256;
  const int SB = (N + 255) / 256;
  const int gG = (N + 63) / 64;
  const int n4 = N * 32;
  const int gAgg = (N + 3) / 4;

  // ---------- contended accumulators zeroed once ----------
  hipMemsetAsync(cnt, 0, 3 * (size_t)N * 4, stream);

  // ---------- CSR + degrees ----------
  hist_kernel<<<gE, 256, 0, stream>>>(row, col, E, cnt, deg);
  scanA_rsqrt_kernel<<<SB, 256, 0, stream>>>(cnt, deg, N, partial, dinv);
  scanB_kernel<<<1, 256, 0, stream>>>(partial, SB, blockoff);
  scanC_kernel<<<SB, 256, 0, stream>>>(cnt, N, blockoff, off, cur, E);
  place_kernel<<<gE, 256, 0, stream>>>(row, col, E, cur, dinv, csr_src, slot_of, wn);

  // ---------- feature layer ----------
  xcvt_stats_kernel<<<CS_BLOCKS, 256, 0, stream>>>(x, xbf, n4, stpX);
  fold_kernel<<<H, H, 0, stream>>>(stpX, CS_BLOCKS, W_feat, b_feat, invN, Wt, cf);
  gemm_kernel<<<gG, 256, 0, stream>>>(xbf, Wt, cf, bufA, N, 1);
  colstats_kernel<<<CS_BLOCKS, 256, 0, stream>>>(bufA, N, stpX);

  // ---------- 3 GCN convs ----------
  for (int i = 0; i < 3; ++i) {
    fold_kernel<<<H, H, 0, stream>>>(stpX, CS_BLOCKS, W_convs + (size_t)i * H * H,
                                     nullptr, invN, Wt, cf);
    gemm_kernel<<<gG, 256, 0, stream>>>(bufA, Wt, cf, bufC, N, 0);
    agg_kernel<<<gAgg, 256, 0, stream>>>(bufC, csr_src, wn, off, dinv,
                                         b_convs + (size_t)i * H, bufA, N);
    if (i < 2) colstats_kernel<<<CS_BLOCKS, 256, 0, stream>>>(bufA, N, stpX);
  }

  // ---------- attention ----------
  natt_kernel<<<gN, 256, 0, stream>>>(bufA, N, W_na, b_na, W_ea, na01, p01, q01);
  eatt_kernel<<<gE, 256, 0, stream>>>(row, col, E, p01, q01, b_ea, slot_of, att0s, degc);
  rsqrt2_kernel<<<gN, 256, 0, stream>>>(deg, degc, dinvc, dinvo, N);
  wa_kernel<<<gE, 256, 0, stream>>>(csr_src, att0s, dinvc, dinvo, wa0, wa1, E);
  xpre_stats_kernel<<<CS_BLOCKS, 256, 0, stream>>>(bufA, na01, bufB, bufC, n4, stpPre);
  // bufA (h) dead now

  // ---------- ctx + obj convs (batched + dual agg) ----------
  fold2_kernel<<<2 * H, H, 0, stream>>>(stpPre, CS_BLOCKS, W_ctx, W_obj, invN, Wt2, cf2);
  gemm2_kernel<<<2 * gG, 256, 0, stream>>>(bufB, bufC, Wt2, cf2, bufD, bufA, N, gG, 0);
  aggdual_kernel<<<gAgg, 256, 0, stream>>>(bufD, bufA, csr_src, wa0, wa1, off, dinvc,
                                           dinvo, b_ctx, b_obj, bufB, bufC, N);
  colstats_kernel<<<CS_BLOCKS, 256, 0, stream>>>(bufB, N, stpC);   // xc
  colstats_kernel<<<CS_BLOCKS, 256, 0, stream>>>(bufC, N, stpO);   // xo

  // ---------- h_co = xc[perm] + xo (+stats) ----------
  permadd_stats_kernel<<<CS_BLOCKS, 256, 0, stream>>>(bufB, bufC, perm, bufD, n4, stpCO);

  // ---------- 3 readouts: heads 0,1 batched; head 2 sequential (mem reuse) ---
  fold3_kernel<<<3 * H, H, 0, stream>>>(stpC, stpO, stpCO, CS_BLOCKS, W_fc1, b_fc1,
                                        invN, Wt3, cf3);
  // z0 (xc head) -> bufA, z1 (xo head) -> xbf
  gemm2_kernel<<<2 * gG, 256, 0, stream>>>(bufB, bufC, Wt3, cf3, bufA, xbf, N, gG, 1);
  colstats3_kernel<<<2 * CS_BLOCKS, 256, 0, stream>>>(bufA, xbf, xbf, N, stpZ);
  fold10x3_kernel<<<2 * NCLS, H, 0, stream>>>(stpZ, CS_BLOCKS, W_fc2, b_fc2, invN,
                                              W2f, c2f);
  fc2x3_kernel<<<2 * gN, 256, 0, stream>>>(bufA, xbf, xbf, W2f, c2f, out, N, gN);
  // head 2 (xco): z2 -> bufA (free after fc2 above)
  gemm_kernel<<<gG, 256, 0, stream>>>(bufD, Wt3 + 2 * (size_t)H * H, cf3 + 2 * H,
                                      bufA, N, 1);
  colstats_kernel<<<CS_BLOCKS, 256, 0, stream>>>(bufA, N, stpZ + 2 * 65536);
  fold10x3_kernel<<<NCLS, H, 0, stream>>>(stpZ + 2 * 65536, CS_BLOCKS,
                                          W_fc2 + 2 * (size_t)H * NCLS, b_fc2 + 2 * NCLS,
                                          invN, W2f + 2 * (size_t)H * NCLS, c2f + 2 * 16);
  fc2x3_kernel<<<gN, 256, 0, stream>>>(bufA, bufA, bufA, W2f + 2 * (size_t)H * NCLS,
                                       c2f + 2 * 16, out + 2 * (size_t)N * NCLS, N, gN);
}